// Round 2
// baseline (822.982 us; speedup 1.0000x reference)
//
#include <hip/hip_runtime.h>
#include <hip/hip_bf16.h>

#define HID 64
#define NGRAPH 64

static inline size_t align256(size_t x) { return (x + 255) & ~(size_t)255; }

// ---- dtype-agnostic float load: f32 ? fp32[i] : bf16[i] ----
__device__ __forceinline__ float ldf(const void* p, size_t i, int f32) {
    if (f32) return ((const float*)p)[i];
    unsigned int w = ((unsigned int)((const unsigned short*)p)[i]) << 16;
    return __uint_as_float(w);
}
__device__ __forceinline__ float bf2f(unsigned short u) {
    return __uint_as_float(((unsigned int)u) << 16);
}
__device__ __forceinline__ unsigned short f2bf(float f) {
    __hip_bfloat16 h = __float2bfloat16(f);
    return *(unsigned short*)&h;
}

// ---------------- dtype sniffer: *flag = 1 if input floats are fp32, 0 if bf16 ----------------
// Interpret first `nwords` uint16 of x as bf16:
//  - true bf16 data (~N(0,0.05)): no values with exponent >= 128, no exact zeros.
//  - fp32 data: even-indexed words are mantissa garbage -> ~50% have exp >= 128.
//  - fp32 data holding bf16-rounded values: even-indexed words are exactly 0.
__global__ void k_sniff(const unsigned short* __restrict__ x, int nwords, int* __restrict__ flag) {
    __shared__ int cw, cz;
    if (threadIdx.x == 0) { cw = 0; cz = 0; }
    __syncthreads();
    int weird = 0, evenzero = 0;
    for (int i = threadIdx.x; i < nwords; i += blockDim.x) {
        unsigned short u = x[i];
        int e = (u >> 7) & 0xFF;
        if (e >= 128) weird++;
        if (((i & 1) == 0) && ((u & 0x7FFF) == 0)) evenzero++;
    }
    atomicAdd(&cw, weird);
    atomicAdd(&cz, evenzero);
    __syncthreads();
    if (threadIdx.x == 0) *flag = (cw > nwords / 16 || cz > nwords / 8) ? 1 : 0;
}

// ---------------- init ----------------
__global__ void k_init(int* cdeg, int* cursor, float* gsum, int* gcnt, int n, int g) {
    int i = blockIdx.x * blockDim.x + threadIdx.x;
    if (i < n) { cdeg[i] = 0; cursor[i] = 0; }
    if (i < g) { gsum[i] = 0.f; gcnt[i] = 0; }
}

// ---------------- degree histogram ----------------
__global__ void k_deg(const int* __restrict__ col, int* __restrict__ cdeg, int e) {
    int i = blockIdx.x * blockDim.x + threadIdx.x;
    if (i < e) atomicAdd(&cdeg[col[i]], 1);
}

// ---------------- exclusive scan (single block) + dis ----------------
__global__ void k_scan(const int* __restrict__ cdeg, int* __restrict__ offs,
                       float* __restrict__ dis, int n) {
    __shared__ int part[256];
    int t = threadIdx.x;
    int chunk = (n + 255) / 256;
    int s = t * chunk;
    int e2 = min(n, s + chunk);
    int sum = 0;
    for (int i = s; i < e2; i++) sum += cdeg[i];
    part[t] = sum;
    __syncthreads();
    if (t == 0) {
        int r = 0;
        for (int i = 0; i < 256; i++) { int v = part[i]; part[i] = r; r += v; }
        offs[n] = r;
    }
    __syncthreads();
    int run = part[t];
    for (int i = s; i < e2; i++) {
        offs[i] = run;
        run += cdeg[i];
        dis[i] = rsqrtf((float)(cdeg[i] + 1));   // +1 self-loop; always > 0
    }
}

// ---------------- CSR fill ----------------
__global__ void k_fill(const int* __restrict__ row, const int* __restrict__ col,
                       const int* __restrict__ offs, int* __restrict__ cursor,
                       int* __restrict__ csr, int e) {
    int i = blockIdx.x * blockDim.x + threadIdx.x;
    if (i < e) {
        int c = col[i];
        int p = atomicAdd(&cursor[c], 1);
        csr[offs[c] + p] = row[i];
    }
}

// ---------------- fused dual GEMM ----------------
// hs = (x@W)*dis (bf16) ; base = (x@W)*dis^2 + x@RW + rb + b (fp32)
// block = 256 = 64 cols x 4 row-groups; 16 rows/block
// XFLAG: x dtype follows *dflag (layer 0); otherwise x is fp32 workspace.
template <int K, bool XFLAG>
__global__ __launch_bounds__(256) void k_gemm(const void* __restrict__ xin,
                                              const void* __restrict__ W,
                                              const void* __restrict__ RW,
                                              const void* __restrict__ bb,
                                              const void* __restrict__ rb,
                                              const float* __restrict__ dis,
                                              const int* __restrict__ dflag,
                                              __hip_bfloat16* __restrict__ hs,
                                              float* __restrict__ base, int n) {
    __shared__ unsigned short sW[K * 64];
    __shared__ unsigned short sR[K * 64];
    __shared__ float sx[16 * K];
    int f32 = *dflag;
    int xf32 = XFLAG ? f32 : 1;
    int tid = threadIdx.x;
    for (int i = tid; i < K * 64; i += 256) {
        sW[i] = f2bf(ldf(W, i, f32));
        sR[i] = f2bf(ldf(RW, i, f32));
    }
    int row0 = blockIdx.x * 16;
    for (int i = tid; i < 16 * K; i += 256) {
        int r = i / K, k = i % K;
        int gr = row0 + r;
        sx[i] = (gr < n) ? ldf(xin, (size_t)gr * K + k, xf32) : 0.f;
    }
    __syncthreads();

    int c = tid & 63;
    int rq = tid >> 6;
    float bc = ldf(bb, c, f32) + ldf(rb, c, f32);
    float ah[4] = {0.f, 0.f, 0.f, 0.f};
    float ar[4] = {0.f, 0.f, 0.f, 0.f};
    for (int k = 0; k < K; k++) {
        float w = bf2f(sW[k * 64 + c]);
        float rw = bf2f(sR[k * 64 + c]);
#pragma unroll
        for (int j = 0; j < 4; j++) {
            float xv = sx[(rq + 4 * j) * K + k];
            ah[j] = fmaf(xv, w, ah[j]);
            ar[j] = fmaf(xv, rw, ar[j]);
        }
    }
#pragma unroll
    for (int j = 0; j < 4; j++) {
        int r = row0 + rq + 4 * j;
        if (r < n) {
            float dv = dis[r];
            float h = ah[j] * dv;
            hs[(size_t)r * 64 + c] = __float2bfloat16(h);
            base[(size_t)r * 64 + c] = h * dv + ar[j] + bc;
        }
    }
}

// ---------------- gather-aggregate + layernorm (+relu) ----------------
// one wave per node, lane = feature channel
__global__ __launch_bounds__(256) void k_agg_ln(const __hip_bfloat16* __restrict__ hs,
                                                const float* __restrict__ base,
                                                const float* __restrict__ dis,
                                                const int* __restrict__ offs,
                                                const int* __restrict__ csr,
                                                const void* __restrict__ gam,
                                                const void* __restrict__ bet,
                                                const int* __restrict__ dflag,
                                                float* __restrict__ xout, int n, int relu) {
    int f32 = *dflag;
    int wave = threadIdx.x >> 6;
    int lane = threadIdx.x & 63;
    int v = blockIdx.x * 4 + wave;
    if (v >= n) return;
    int s = offs[v];
    int e2 = offs[v + 1];
    float acc = 0.f;
    for (int i = s; i < e2; i++) {
        int src = csr[i];
        acc += __bfloat162float(hs[(size_t)src * 64 + lane]);
    }
    acc = base[(size_t)v * 64 + lane] + dis[v] * acc;
    // layernorm over 64 lanes
    float m = acc;
#pragma unroll
    for (int o = 32; o > 0; o >>= 1) m += __shfl_xor(m, o, 64);
    m *= (1.f / 64.f);
    float d = acc - m;
    float var = d * d;
#pragma unroll
    for (int o = 32; o > 0; o >>= 1) var += __shfl_xor(var, o, 64);
    var *= (1.f / 64.f);
    float rs = rsqrtf(var + 1e-5f);
    float y = d * rs * ldf(gam, lane, f32) + ldf(bet, lane, f32);
    if (relu) y = fmaxf(y, 0.f);
    xout[(size_t)v * 64 + lane] = y;
}

// ---------------- readout ----------------
__global__ __launch_bounds__(256) void k_readout(const float* __restrict__ x,
                                                 const int* __restrict__ batch,
                                                 const void* __restrict__ lw,
                                                 const int* __restrict__ dflag,
                                                 float* __restrict__ gsum, int* __restrict__ gcnt,
                                                 int n) {
    __shared__ float sG[NGRAPH];
    __shared__ int sC[NGRAPH];
    int f32 = *dflag;
    int t = threadIdx.x;
    if (t < NGRAPH) { sG[t] = 0.f; sC[t] = 0; }
    __syncthreads();
    int wave = t >> 6;
    int lane = t & 63;
    int v = blockIdx.x * 4 + wave;
    if (v < n) {
        float val = x[(size_t)v * 64 + lane] * ldf(lw, lane, f32);
#pragma unroll
        for (int o = 32; o > 0; o >>= 1) val += __shfl_xor(val, o, 64);
        if (lane == 0) {
            int b = batch[v];
            atomicAdd(&sG[b], val);
            atomicAdd(&sC[b], 1);
        }
    }
    __syncthreads();
    if (t < NGRAPH && sC[t] > 0) {
        atomicAdd(&gsum[t], sG[t]);
        atomicAdd(&gcnt[t], sC[t]);
    }
}

// ---------------- finalize (output dtype follows flag) ----------------
__global__ void k_final(const float* __restrict__ gsum, const int* __restrict__ gcnt,
                        const void* __restrict__ lb, const int* __restrict__ dflag,
                        void* __restrict__ out, int g) {
    int f32 = *dflag;
    int i = threadIdx.x;
    if (i < g) {
        float c = fmaxf((float)gcnt[i], 1.f);
        float v = gsum[i] / c + ldf(lb, 0, f32);
        if (f32) ((float*)out)[i] = v;
        else ((__hip_bfloat16*)out)[i] = __float2bfloat16(v);
    }
}

extern "C" void kernel_launch(void* const* d_in, const int* in_sizes, int n_in,
                              void* d_out, int out_size, void* d_ws, size_t ws_size,
                              hipStream_t stream) {
    const void* x_in = d_in[0];
    const int* edge_index = (const int*)d_in[1];
    const int* batch = (const int*)d_in[2];
    const void *W0 = d_in[3], *b0 = d_in[4], *W1 = d_in[5], *b1 = d_in[6],
               *W2 = d_in[7], *b2 = d_in[8];
    const void *RW0 = d_in[9], *rb0 = d_in[10], *RW1 = d_in[11], *rb1 = d_in[12],
               *RW2 = d_in[13], *rb2 = d_in[14];
    const void *g0 = d_in[15], *be0 = d_in[16], *g1 = d_in[17], *be1 = d_in[18],
               *g2 = d_in[19], *be2 = d_in[20], *lw = d_in[21], *lb = d_in[22];

    const int N = in_sizes[2];          // nodes
    const int E = in_sizes[1] / 2;      // edges
    const int FIN = in_sizes[0] / N;    // input feature dim (128)
    const int* erow = edge_index;       // sources
    const int* ecol = edge_index + E;   // targets

    // workspace carve (~36 MB worst case)
    char* p = (char*)d_ws;
    size_t off = 0;
    float* dis = (float*)(p + off);  off = align256(off + (size_t)N * 4);
    int* cdeg = (int*)(p + off);     off = align256(off + (size_t)N * 4);
    int* cursor = (int*)(p + off);   off = align256(off + (size_t)N * 4);
    int* offs = (int*)(p + off);     off = align256(off + (size_t)(N + 1) * 4);
    int* csr = (int*)(p + off);      off = align256(off + (size_t)E * 4);
    __hip_bfloat16* hs = (__hip_bfloat16*)(p + off); off = align256(off + (size_t)N * HID * 2);
    float* base = (float*)(p + off); off = align256(off + (size_t)N * HID * 4);
    float* xbuf = (float*)(p + off); off = align256(off + (size_t)N * HID * 4);
    float* gsum = (float*)(p + off); off = align256(off + (size_t)NGRAPH * 4);
    int* gcnt = (int*)(p + off);     off = align256(off + (size_t)NGRAPH * 4);
    int* dflag = (int*)(p + off);    off = align256(off + 4);
    (void)ws_size;

    const int TB = 256;
    int nb_n = (N + TB - 1) / TB;
    int nb_e = (E + TB - 1) / TB;
    int nb_gemm = (N + 15) / 16;
    int nb_node4 = (N + 3) / 4;

    k_sniff<<<1, 256, 0, stream>>>((const unsigned short*)x_in, 8192, dflag);
    k_init<<<nb_n, TB, 0, stream>>>(cdeg, cursor, gsum, gcnt, N, NGRAPH);
    k_deg<<<nb_e, TB, 0, stream>>>(ecol, cdeg, E);
    k_scan<<<1, TB, 0, stream>>>(cdeg, offs, dis, N);
    k_fill<<<nb_e, TB, 0, stream>>>(erow, ecol, offs, cursor, csr, E);

    // layer 0 (K=128, x dtype per flag)
    k_gemm<128, true><<<nb_gemm, TB, 0, stream>>>(x_in, W0, RW0, b0, rb0, dis, dflag, hs, base, N);
    k_agg_ln<<<nb_node4, TB, 0, stream>>>(hs, base, dis, offs, csr, g0, be0, dflag, xbuf, N, 1);
    // layer 1 (K=64, x fp32 workspace)
    k_gemm<64, false><<<nb_gemm, TB, 0, stream>>>(xbuf, W1, RW1, b1, rb1, dis, dflag, hs, base, N);
    k_agg_ln<<<nb_node4, TB, 0, stream>>>(hs, base, dis, offs, csr, g1, be1, dflag, xbuf, N, 1);
    // layer 2 (no relu)
    k_gemm<64, false><<<nb_gemm, TB, 0, stream>>>(xbuf, W2, RW2, b2, rb2, dis, dflag, hs, base, N);
    k_agg_ln<<<nb_node4, TB, 0, stream>>>(hs, base, dis, offs, csr, g2, be2, dflag, xbuf, N, 0);

    // readout
    k_readout<<<nb_node4, TB, 0, stream>>>(xbuf, batch, lw, dflag, gsum, gcnt, N);
    k_final<<<1, 64, 0, stream>>>(gsum, gcnt, lb, dflag, d_out, NGRAPH);
}

// Round 3
// 799.889 us; speedup vs baseline: 1.0289x; 1.0289x over previous
//
#include <hip/hip_runtime.h>
#include <hip/hip_bf16.h>

#define HID 64
#define NGRAPH 64

static inline size_t align256(size_t x) { return (x + 255) & ~(size_t)255; }

typedef __attribute__((ext_vector_type(8))) short bf16x8;
typedef __attribute__((ext_vector_type(4))) float f32x4;

// ---- dtype-agnostic float load: f32 ? fp32[i] : bf16[i] ----
__device__ __forceinline__ float ldf(const void* p, size_t i, int f32) {
    if (f32) return ((const float*)p)[i];
    unsigned int w = ((unsigned int)((const unsigned short*)p)[i]) << 16;
    return __uint_as_float(w);
}
__device__ __forceinline__ float bf2f(unsigned short u) {
    return __uint_as_float(((unsigned int)u) << 16);
}
__device__ __forceinline__ unsigned short f2bf(float f) {
    __hip_bfloat16 h = __float2bfloat16(f);
    return *(unsigned short*)&h;
}

// ---------------- dtype sniffer (see round-1 notes) ----------------
__global__ void k_sniff(const unsigned short* __restrict__ x, int nwords, int* __restrict__ flag) {
    __shared__ int cw, cz;
    if (threadIdx.x == 0) { cw = 0; cz = 0; }
    __syncthreads();
    int weird = 0, evenzero = 0;
    for (int i = threadIdx.x; i < nwords; i += blockDim.x) {
        unsigned short u = x[i];
        int e = (u >> 7) & 0xFF;
        if (e >= 128) weird++;
        if (((i & 1) == 0) && ((u & 0x7FFF) == 0)) evenzero++;
    }
    atomicAdd(&cw, weird);
    atomicAdd(&cz, evenzero);
    __syncthreads();
    if (threadIdx.x == 0) *flag = (cw > nwords / 16 || cz > nwords / 8) ? 1 : 0;
}

// ---------------- init ----------------
__global__ void k_init(int* cdeg, int* cursor, float* gsum, int* gcnt, int n, int g) {
    int i = blockIdx.x * blockDim.x + threadIdx.x;
    if (i < n) { cdeg[i] = 0; cursor[i] = 0; }
    if (i < g) { gsum[i] = 0.f; gcnt[i] = 0; }
}

// ---------------- weight pack: Wt[n][k] bf16 (n<64: W col n; n>=64: RW col n-64), bcat = b+rb ----------------
__global__ void k_pack(const void* W0, const void* RW0, const void* b0, const void* rb0,
                       const void* W1, const void* RW1, const void* b1, const void* rb1,
                       const void* W2, const void* RW2, const void* b2, const void* rb2,
                       const int* __restrict__ dflag,
                       unsigned short* wt0, unsigned short* wt1, unsigned short* wt2,
                       float* bcat) {
    int f = *dflag;
    int i = blockIdx.x * blockDim.x + threadIdx.x;
    if (i < 16384) {                       // layer0: 128 cols x 128 k
        int n = i >> 7, k = i & 127;
        float v = (n < 64) ? ldf(W0, (size_t)k * 64 + n, f) : ldf(RW0, (size_t)k * 64 + (n - 64), f);
        wt0[n * 128 + k] = f2bf(v);
    } else if (i < 24576) {                // layer1: 128 cols x 64 k
        int j = i - 16384; int n = j >> 6, k = j & 63;
        float v = (n < 64) ? ldf(W1, (size_t)k * 64 + n, f) : ldf(RW1, (size_t)k * 64 + (n - 64), f);
        wt1[n * 64 + k] = f2bf(v);
    } else if (i < 32768) {                // layer2
        int j = i - 24576; int n = j >> 6, k = j & 63;
        float v = (n < 64) ? ldf(W2, (size_t)k * 64 + n, f) : ldf(RW2, (size_t)k * 64 + (n - 64), f);
        wt2[n * 64 + k] = f2bf(v);
    } else if (i < 32768 + 192) {          // biases
        int j = i - 32768; int l = j >> 6, c = j & 63;
        const void* bb = (l == 0) ? b0 : (l == 1) ? b1 : b2;
        const void* rr = (l == 0) ? rb0 : (l == 1) ? rb1 : rb2;
        bcat[l * 64 + c] = ldf(bb, c, f) + ldf(rr, c, f);
    }
}

// ---------------- degree histogram + per-graph node counts ----------------
__global__ void k_deg(const int* __restrict__ col, int* __restrict__ cdeg, int e,
                      const int* __restrict__ batch, int* __restrict__ gcnt, int n) {
    int i = blockIdx.x * blockDim.x + threadIdx.x;
    if (i < e) atomicAdd(&cdeg[col[i]], 1);
    if (i < n) atomicAdd(&gcnt[batch[i]], 1);
}

// ---------------- hierarchical scan: 1024 elems per block ----------------
__global__ void k_scan1(const int* __restrict__ cdeg, int* __restrict__ bsum, int n) {
    __shared__ int s[256];
    int t = threadIdx.x;
    int base = blockIdx.x * 1024 + t * 4;
    int sum = 0;
#pragma unroll
    for (int j = 0; j < 4; j++) { int i = base + j; if (i < n) sum += cdeg[i]; }
    s[t] = sum;
    __syncthreads();
    for (int o = 128; o > 0; o >>= 1) {
        if (t < o) s[t] += s[t + o];
        __syncthreads();
    }
    if (t == 0) bsum[blockIdx.x] = s[0];
}

__global__ void k_scan2(const int* __restrict__ bsum, int* __restrict__ bscan,
                        int* __restrict__ offs, int nb, int n) {
    __shared__ int s[256];
    int t = threadIdx.x;
    int v = (t < nb) ? bsum[t] : 0;
    s[t] = v;
    __syncthreads();
    for (int o = 1; o < 256; o <<= 1) {
        int x = (t >= o) ? s[t - o] : 0;
        __syncthreads();
        s[t] += x;
        __syncthreads();
    }
    if (t < nb) bscan[t] = s[t] - v;        // exclusive
    if (t == nb - 1) offs[n] = s[t];        // total = E
}

__global__ void k_scan3(const int* __restrict__ cdeg, const int* __restrict__ bscan,
                        int* __restrict__ offs, float* __restrict__ dis, int n) {
    __shared__ int s[256];
    int t = threadIdx.x;
    int base = blockIdx.x * 1024 + t * 4;
    int tsum = 0;
#pragma unroll
    for (int j = 0; j < 4; j++) { int i = base + j; if (i < n) tsum += cdeg[i]; }
    s[t] = tsum;
    __syncthreads();
    for (int o = 1; o < 256; o <<= 1) {
        int x = (t >= o) ? s[t - o] : 0;
        __syncthreads();
        s[t] += x;
        __syncthreads();
    }
    int off = bscan[blockIdx.x] + s[t] - tsum;
#pragma unroll
    for (int j = 0; j < 4; j++) {
        int i = base + j;
        if (i < n) {
            offs[i] = off;
            off += cdeg[i];
            dis[i] = rsqrtf((float)(cdeg[i] + 1));
        }
    }
}

// ---------------- CSR fill ----------------
__global__ void k_fill(const int* __restrict__ row, const int* __restrict__ col,
                       const int* __restrict__ offs, int* __restrict__ cursor,
                       int* __restrict__ csr, int e) {
    int i = blockIdx.x * blockDim.x + threadIdx.x;
    if (i < e) {
        int c = col[i];
        int p = atomicAdd(&cursor[c], 1);
        csr[offs[c] + p] = row[i];
    }
}

// ---------------- MFMA dual GEMM ----------------
// out cols 0..63 = x@W, 64..127 = x@RW (packed Wt). 64 rows/block, 4 waves,
// wave w rows [w*16,w*16+16), 8 col-tiles of 16. hi/lo bf16 split of x when LO.
// LDS rows padded +8 shorts (16B) -> 2-way bank aliasing only (free).
template <int K, bool XFLAG, bool LO>
__global__ __launch_bounds__(256) void k_gemm(const void* __restrict__ xin,
                                              const unsigned short* __restrict__ wt,
                                              const float* __restrict__ bcat,
                                              const float* __restrict__ dis,
                                              const int* __restrict__ dflag,
                                              __hip_bfloat16* __restrict__ hs,
                                              float* __restrict__ base, int n) {
    const int KP = K + 8;                   // padded row (shorts)
    __shared__ unsigned short sXh[64 * KP];
    __shared__ unsigned short sXl[LO ? 64 * KP : 1];
    __shared__ unsigned short sW[128 * KP];
    int f32 = *dflag;
    int xf32 = XFLAG ? f32 : 1;
    int tid = threadIdx.x;
    int row0 = blockIdx.x * 64;

    // stage packed weights (bf16, contiguous) as uint4, row-remapped for pad
    {
        const uint4* src = (const uint4*)wt;
        uint4* dst = (uint4*)sW;
        const int C = K / 8;                 // uint4 per packed row
        const int CP = KP / 8;               // uint4 per padded row
        for (int i = tid; i < 128 * C; i += 256) {
            int nrow = i / C, c = i % C;
            dst[nrow * CP + c] = src[i];
        }
    }
    // stage x with hi/lo split
    for (int i = tid; i < 64 * K; i += 256) {
        int r = i / K, k = i - r * K;
        int gr = row0 + r;
        float v = (gr < n) ? ldf(xin, (size_t)gr * K + k, xf32) : 0.f;
        unsigned short h = f2bf(v);
        sXh[r * KP + k] = h;
        if (LO) sXl[r * KP + k] = f2bf(v - bf2f(h));
    }
    __syncthreads();

    int w = tid >> 6, lane = tid & 63;
    int m = lane & 15, q = lane >> 4;
    f32x4 acc[8];
#pragma unroll
    for (int ct = 0; ct < 8; ct++) acc[ct] = (f32x4){0.f, 0.f, 0.f, 0.f};

    int arow = w * 16 + m;
#pragma unroll
    for (int ks = 0; ks < K / 32; ks++) {
        int ka = ks * 32 + q * 8;
        bf16x8 ah = *(const bf16x8*)&sXh[arow * KP + ka];
        bf16x8 al;
        if (LO) al = *(const bf16x8*)&sXl[arow * KP + ka];
#pragma unroll
        for (int ct = 0; ct < 8; ct++) {
            bf16x8 bb = *(const bf16x8*)&sW[(ct * 16 + m) * KP + ka];
            acc[ct] = __builtin_amdgcn_mfma_f32_16x16x32_bf16(ah, bb, acc[ct], 0, 0, 0);
            if (LO) acc[ct] = __builtin_amdgcn_mfma_f32_16x16x32_bf16(al, bb, acc[ct], 0, 0, 0);
        }
    }

    // epilogue: C layout col=lane&15, row=(lane>>4)*4+reg
#pragma unroll
    for (int ct = 0; ct < 4; ct++) {
        int col = ct * 16 + m;
#pragma unroll
        for (int reg = 0; reg < 4; reg++) {
            int r = row0 + w * 16 + q * 4 + reg;
            if (r < n) {
                float dv = dis[r];
                float h = acc[ct][reg] * dv;
                hs[(size_t)r * 64 + col] = __float2bfloat16(h);
                base[(size_t)r * 64 + col] = h * dv + acc[ct + 4][reg] + bcat[col];
            }
        }
    }
}

// ---------------- gather-aggregate + layernorm (+relu) [+fused readout] ----------------
template <bool FINAL>
__global__ __launch_bounds__(256) void k_agg_ln(const __hip_bfloat16* __restrict__ hs,
                                                const float* __restrict__ base,
                                                const float* __restrict__ dis,
                                                const int* __restrict__ offs,
                                                const int* __restrict__ csr,
                                                const void* __restrict__ gam,
                                                const void* __restrict__ bet,
                                                const int* __restrict__ dflag,
                                                float* __restrict__ xout, int n, int relu,
                                                const int* __restrict__ batch,
                                                const void* __restrict__ lw,
                                                float* __restrict__ gsum) {
    __shared__ float sG[FINAL ? NGRAPH : 1];
    int f32 = *dflag;
    int t = threadIdx.x;
    if (FINAL) {
        if (t < NGRAPH) sG[t] = 0.f;
        __syncthreads();
    }
    int wave = t >> 6;
    int lane = t & 63;
    int v = blockIdx.x * 4 + wave;
    if (!FINAL && v >= n) return;
    if (v < n) {
        int s = offs[v];
        int e2 = offs[v + 1];
        float acc = 0.f;
        for (int i = s; i < e2; i++) {
            int src = csr[i];
            acc += __bfloat162float(hs[(size_t)src * 64 + lane]);
        }
        acc = base[(size_t)v * 64 + lane] + dis[v] * acc;
        float m = acc;
#pragma unroll
        for (int o = 32; o > 0; o >>= 1) m += __shfl_xor(m, o, 64);
        m *= (1.f / 64.f);
        float d = acc - m;
        float var = d * d;
#pragma unroll
        for (int o = 32; o > 0; o >>= 1) var += __shfl_xor(var, o, 64);
        var *= (1.f / 64.f);
        float rs = rsqrtf(var + 1e-5f);
        float y = d * rs * ldf(gam, lane, f32) + ldf(bet, lane, f32);
        if (relu) y = fmaxf(y, 0.f);
        if (!FINAL) {
            xout[(size_t)v * 64 + lane] = y;
        } else {
            float val = y * ldf(lw, lane, f32);
#pragma unroll
            for (int o = 32; o > 0; o >>= 1) val += __shfl_xor(val, o, 64);
            if (lane == 0) atomicAdd(&sG[batch[v]], val);
        }
    }
    if (FINAL) {
        __syncthreads();
        if (t < NGRAPH && sG[t] != 0.f) atomicAdd(&gsum[t], sG[t]);
    }
}

// ---------------- finalize ----------------
__global__ void k_final(const float* __restrict__ gsum, const int* __restrict__ gcnt,
                        const void* __restrict__ lb, const int* __restrict__ dflag,
                        void* __restrict__ out, int g) {
    int f32 = *dflag;
    int i = threadIdx.x;
    if (i < g) {
        float c = fmaxf((float)gcnt[i], 1.f);
        float v = gsum[i] / c + ldf(lb, 0, f32);
        if (f32) ((float*)out)[i] = v;
        else ((__hip_bfloat16*)out)[i] = __float2bfloat16(v);
    }
}

extern "C" void kernel_launch(void* const* d_in, const int* in_sizes, int n_in,
                              void* d_out, int out_size, void* d_ws, size_t ws_size,
                              hipStream_t stream) {
    const void* x_in = d_in[0];
    const int* edge_index = (const int*)d_in[1];
    const int* batch = (const int*)d_in[2];
    const void *W0 = d_in[3], *b0 = d_in[4], *W1 = d_in[5], *b1 = d_in[6],
               *W2 = d_in[7], *b2 = d_in[8];
    const void *RW0 = d_in[9], *rb0 = d_in[10], *RW1 = d_in[11], *rb1 = d_in[12],
               *RW2 = d_in[13], *rb2 = d_in[14];
    const void *g0 = d_in[15], *be0 = d_in[16], *g1 = d_in[17], *be1 = d_in[18],
               *g2 = d_in[19], *be2 = d_in[20], *lw = d_in[21], *lb = d_in[22];

    const int N = in_sizes[2];
    const int E = in_sizes[1] / 2;
    const int* erow = edge_index;
    const int* ecol = edge_index + E;

    // workspace carve (~37 MB)
    char* p = (char*)d_ws;
    size_t off = 0;
    float* dis = (float*)(p + off);  off = align256(off + (size_t)N * 4);
    int* cdeg = (int*)(p + off);     off = align256(off + (size_t)N * 4);
    int* cursor = (int*)(p + off);   off = align256(off + (size_t)N * 4);
    int* offs = (int*)(p + off);     off = align256(off + (size_t)(N + 1) * 4);
    int* csr = (int*)(p + off);      off = align256(off + (size_t)E * 4);
    __hip_bfloat16* hs = (__hip_bfloat16*)(p + off); off = align256(off + (size_t)N * HID * 2);
    float* base = (float*)(p + off); off = align256(off + (size_t)N * HID * 4);
    float* xbuf = (float*)(p + off); off = align256(off + (size_t)N * HID * 4);
    unsigned short* wt0 = (unsigned short*)(p + off); off = align256(off + 16384 * 2);
    unsigned short* wt1 = (unsigned short*)(p + off); off = align256(off + 8192 * 2);
    unsigned short* wt2 = (unsigned short*)(p + off); off = align256(off + 8192 * 2);
    float* bcat = (float*)(p + off); off = align256(off + 192 * 4);
    int* bsum = (int*)(p + off);     off = align256(off + 256 * 4);
    int* bscan = (int*)(p + off);    off = align256(off + 256 * 4);
    float* gsum = (float*)(p + off); off = align256(off + NGRAPH * 4);
    int* gcnt = (int*)(p + off);     off = align256(off + NGRAPH * 4);
    int* dflag = (int*)(p + off);    off = align256(off + 4);
    (void)ws_size;

    const int TB = 256;
    int nb_n = (N + TB - 1) / TB;
    int nb_en = (((E > N) ? E : N) + TB - 1) / TB;
    int nb_e = (E + TB - 1) / TB;
    int nb1 = (N + 1023) / 1024;
    int nb_gemm = (N + 63) / 64;
    int nb_node4 = (N + 3) / 4;

    k_sniff<<<1, 256, 0, stream>>>((const unsigned short*)x_in, 8192, dflag);
    k_init<<<nb_n, TB, 0, stream>>>(cdeg, cursor, gsum, gcnt, N, NGRAPH);
    k_pack<<<130, TB, 0, stream>>>(W0, RW0, b0, rb0, W1, RW1, b1, rb1, W2, RW2, b2, rb2,
                                   dflag, wt0, wt1, wt2, bcat);
    k_deg<<<nb_en, TB, 0, stream>>>(ecol, cdeg, E, batch, gcnt, N);
    k_scan1<<<nb1, TB, 0, stream>>>(cdeg, bsum, N);
    k_scan2<<<1, TB, 0, stream>>>(bsum, bscan, offs, nb1, N);
    k_scan3<<<nb1, TB, 0, stream>>>(cdeg, bscan, offs, dis, N);
    k_fill<<<nb_e, TB, 0, stream>>>(erow, ecol, offs, cursor, csr, E);

    // layer 0 (K=128, x dtype per flag, no lo split: input already bf16 in bf16-world)
    k_gemm<128, true, false><<<nb_gemm, TB, 0, stream>>>(x_in, wt0, bcat, dis, dflag, hs, base, N);
    k_agg_ln<false><<<nb_node4, TB, 0, stream>>>(hs, base, dis, offs, csr, g0, be0, dflag,
                                                 xbuf, N, 1, nullptr, nullptr, nullptr);
    // layer 1 (K=64, fp32 x, hi/lo split)
    k_gemm<64, false, true><<<nb_gemm, TB, 0, stream>>>(xbuf, wt1, bcat + 64, dis, dflag, hs, base, N);
    k_agg_ln<false><<<nb_node4, TB, 0, stream>>>(hs, base, dis, offs, csr, g1, be1, dflag,
                                                 xbuf, N, 1, nullptr, nullptr, nullptr);
    // layer 2 (no relu, fused readout)
    k_gemm<64, false, true><<<nb_gemm, TB, 0, stream>>>(xbuf, wt2, bcat + 128, dis, dflag, hs, base, N);
    k_agg_ln<true><<<nb_node4, TB, 0, stream>>>(hs, base, dis, offs, csr, g2, be2, dflag,
                                                nullptr, N, 0, batch, lw, gsum);

    k_final<<<1, 64, 0, stream>>>(gsum, gcnt, lb, dflag, d_out, NGRAPH);
}

// Round 4
// 742.270 us; speedup vs baseline: 1.1087x; 1.0776x over previous
//
#include <hip/hip_runtime.h>
#include <hip/hip_bf16.h>

#define HID 64
#define NGRAPH 64
#define RPB 512          // nodes owned per block in ownership kernels

static inline size_t align256(size_t x) { return (x + 255) & ~(size_t)255; }

typedef __attribute__((ext_vector_type(8))) short bf16x8;
typedef __attribute__((ext_vector_type(4))) float f32x4;

// ---- dtype-agnostic float load: f32 ? fp32[i] : bf16[i] ----
__device__ __forceinline__ float ldf(const void* p, size_t i, int f32) {
    if (f32) return ((const float*)p)[i];
    unsigned int w = ((unsigned int)((const unsigned short*)p)[i]) << 16;
    return __uint_as_float(w);
}
__device__ __forceinline__ float bf2f(unsigned short u) {
    return __uint_as_float(((unsigned int)u) << 16);
}
__device__ __forceinline__ unsigned short f2bf(float f) {
    __hip_bfloat16 h = __float2bfloat16(f);
    return *(unsigned short*)&h;
}

// ---------------- dtype sniffer + zero small accumulators ----------------
__global__ void k_sniff(const unsigned short* __restrict__ x, int nwords, int* __restrict__ flag,
                        float* __restrict__ gsum, int* __restrict__ gcnt) {
    __shared__ int cw, cz;
    int t = threadIdx.x;
    if (t == 0) { cw = 0; cz = 0; }
    if (t < NGRAPH) { gsum[t] = 0.f; gcnt[t] = 0; }
    __syncthreads();
    int weird = 0, evenzero = 0;
    for (int i = t; i < nwords; i += blockDim.x) {
        unsigned short u = x[i];
        int e = (u >> 7) & 0xFF;
        if (e >= 128) weird++;
        if (((i & 1) == 0) && ((u & 0x7FFF) == 0)) evenzero++;
    }
    atomicAdd(&cw, weird);
    atomicAdd(&cz, evenzero);
    __syncthreads();
    if (t == 0) *flag = (cw > nwords / 16 || cz > nwords / 8) ? 1 : 0;
}

// ---------------- per-graph node counts: LDS hist (batch sorted -> few spill atomics) ----------------
__global__ void k_gcnt(const int* __restrict__ batch, int* __restrict__ gcnt, int n) {
    __shared__ int h[NGRAPH];
    int t = threadIdx.x;
    if (t < NGRAPH) h[t] = 0;
    __syncthreads();
    int i = blockIdx.x * blockDim.x + t;
    if (i < n) atomicAdd(&h[batch[i]], 1);
    __syncthreads();
    if (t < NGRAPH && h[t] > 0) atomicAdd(&gcnt[t], h[t]);
}

// ---------------- weight pack: Wt[n][k] bf16 (n<64: W col n; n>=64: RW col n-64), bcat = b+rb ----------------
__global__ void k_pack(const void* W0, const void* RW0, const void* b0, const void* rb0,
                       const void* W1, const void* RW1, const void* b1, const void* rb1,
                       const void* W2, const void* RW2, const void* b2, const void* rb2,
                       const int* __restrict__ dflag,
                       unsigned short* wt0, unsigned short* wt1, unsigned short* wt2,
                       float* bcat) {
    int f = *dflag;
    int i = blockIdx.x * blockDim.x + threadIdx.x;
    if (i < 16384) {                       // layer0: 128 cols x 128 k
        int n = i >> 7, k = i & 127;
        float v = (n < 64) ? ldf(W0, (size_t)k * 64 + n, f) : ldf(RW0, (size_t)k * 64 + (n - 64), f);
        wt0[n * 128 + k] = f2bf(v);
    } else if (i < 24576) {                // layer1: 128 cols x 64 k
        int j = i - 16384; int n = j >> 6, k = j & 63;
        float v = (n < 64) ? ldf(W1, (size_t)k * 64 + n, f) : ldf(RW1, (size_t)k * 64 + (n - 64), f);
        wt1[n * 64 + k] = f2bf(v);
    } else if (i < 32768) {                // layer2
        int j = i - 24576; int n = j >> 6, k = j & 63;
        float v = (n < 64) ? ldf(W2, (size_t)k * 64 + n, f) : ldf(RW2, (size_t)k * 64 + (n - 64), f);
        wt2[n * 64 + k] = f2bf(v);
    } else if (i < 32768 + 192) {          // biases
        int j = i - 32768; int l = j >> 6, c = j & 63;
        const void* bb = (l == 0) ? b0 : (l == 1) ? b1 : b2;
        const void* rr = (l == 0) ? rb0 : (l == 1) ? rb1 : rb2;
        bcat[l * 64 + c] = ldf(bb, c, f) + ldf(rr, c, f);
    }
}

// ---------------- degree count, ownership-partitioned (NO global atomics) ----------------
// block b owns nodes [b*RPB, b*RPB+RPB); scans all edge targets, LDS histogram.
__global__ __launch_bounds__(1024) void k_count(const int* __restrict__ ecol,
                                                int* __restrict__ cdeg, int e, int n) {
    __shared__ int sh[RPB];
    int t = threadIdx.x;
    int base = blockIdx.x * RPB;
    int lim = n - base; if (lim > RPB) lim = RPB;
    if (lim <= 0) return;
    for (int i = t; i < RPB; i += 1024) sh[i] = 0;
    __syncthreads();
    if ((e & 3) == 0) {
        const int4* e4 = (const int4*)ecol;
        int n4 = e >> 2;
        for (int i = t; i < n4; i += 1024) {
            int4 c4 = e4[i];
            int c;
            c = c4.x - base; if ((unsigned)c < (unsigned)lim) atomicAdd(&sh[c], 1);
            c = c4.y - base; if ((unsigned)c < (unsigned)lim) atomicAdd(&sh[c], 1);
            c = c4.z - base; if ((unsigned)c < (unsigned)lim) atomicAdd(&sh[c], 1);
            c = c4.w - base; if ((unsigned)c < (unsigned)lim) atomicAdd(&sh[c], 1);
        }
    } else {
        for (int i = t; i < e; i += 1024) {
            int c = ecol[i] - base;
            if ((unsigned)c < (unsigned)lim) atomicAdd(&sh[c], 1);
        }
    }
    __syncthreads();
    for (int i = t; i < lim; i += 1024) cdeg[base + i] = sh[i];
}

// ---------------- hierarchical scan ----------------
__global__ void k_scan1(const int* __restrict__ cdeg, int* __restrict__ bsum, int n) {
    __shared__ int s[256];
    int t = threadIdx.x;
    int base = blockIdx.x * 1024 + t * 4;
    int sum = 0;
#pragma unroll
    for (int j = 0; j < 4; j++) { int i = base + j; if (i < n) sum += cdeg[i]; }
    s[t] = sum;
    __syncthreads();
    for (int o = 128; o > 0; o >>= 1) {
        if (t < o) s[t] += s[t + o];
        __syncthreads();
    }
    if (t == 0) bsum[blockIdx.x] = s[0];
}

__global__ void k_scan2(const int* __restrict__ bsum, int* __restrict__ bscan,
                        int* __restrict__ offs, int nb, int n) {
    __shared__ int s[256];
    int t = threadIdx.x;
    int v = (t < nb) ? bsum[t] : 0;
    s[t] = v;
    __syncthreads();
    for (int o = 1; o < 256; o <<= 1) {
        int x = (t >= o) ? s[t - o] : 0;
        __syncthreads();
        s[t] += x;
        __syncthreads();
    }
    if (t < nb) bscan[t] = s[t] - v;        // exclusive
    if (t == nb - 1) offs[n] = s[t];        // total = E
}

__global__ void k_scan3(const int* __restrict__ cdeg, const int* __restrict__ bscan,
                        int* __restrict__ offs, float* __restrict__ dis, int n) {
    __shared__ int s[256];
    int t = threadIdx.x;
    int base = blockIdx.x * 1024 + t * 4;
    int tsum = 0;
#pragma unroll
    for (int j = 0; j < 4; j++) { int i = base + j; if (i < n) tsum += cdeg[i]; }
    s[t] = tsum;
    __syncthreads();
    for (int o = 1; o < 256; o <<= 1) {
        int x = (t >= o) ? s[t - o] : 0;
        __syncthreads();
        s[t] += x;
        __syncthreads();
    }
    int off = bscan[blockIdx.x] + s[t] - tsum;
#pragma unroll
    for (int j = 0; j < 4; j++) {
        int i = base + j;
        if (i < n) {
            offs[i] = off;
            off += cdeg[i];
            dis[i] = rsqrtf((float)(cdeg[i] + 1));
        }
    }
}

// ---------------- CSR fill, ownership-partitioned (LDS cursors, no global atomics) ----------------
__global__ __launch_bounds__(1024) void k_fillown(const int* __restrict__ erow,
                                                  const int* __restrict__ ecol,
                                                  const int* __restrict__ offs,
                                                  int* __restrict__ csr, int e, int n) {
    __shared__ int scur[RPB];
    __shared__ int soff[RPB];
    int t = threadIdx.x;
    int base = blockIdx.x * RPB;
    int lim = n - base; if (lim > RPB) lim = RPB;
    if (lim <= 0) return;
    for (int i = t; i < RPB; i += 1024) {
        scur[i] = 0;
        soff[i] = (i < lim) ? offs[base + i] : 0;
    }
    __syncthreads();
    if ((e & 3) == 0) {
        const int4* e4 = (const int4*)ecol;
        int n4 = e >> 2;
        for (int i = t; i < n4; i += 1024) {
            int4 c4 = e4[i];
#pragma unroll
            for (int j = 0; j < 4; j++) {
                int c = ((j == 0) ? c4.x : (j == 1) ? c4.y : (j == 2) ? c4.z : c4.w) - base;
                if ((unsigned)c < (unsigned)lim) {
                    int p = atomicAdd(&scur[c], 1);
                    csr[soff[c] + p] = erow[i * 4 + j];
                }
            }
        }
    } else {
        for (int i = t; i < e; i += 1024) {
            int c = ecol[i] - base;
            if ((unsigned)c < (unsigned)lim) {
                int p = atomicAdd(&scur[c], 1);
                csr[soff[c] + p] = erow[i];
            }
        }
    }
}

// ---------------- MFMA dual GEMM ----------------
// out cols 0..63 = x@W, 64..127 = x@RW (packed Wt). 64 rows/block, 4 waves,
// wave w rows [w*16,w*16+16), 8 col-tiles of 16. hi/lo bf16 split of x when LO.
template <int K, bool XFLAG, bool LO>
__global__ __launch_bounds__(256) void k_gemm(const void* __restrict__ xin,
                                              const unsigned short* __restrict__ wt,
                                              const float* __restrict__ bcat,
                                              const float* __restrict__ dis,
                                              const int* __restrict__ dflag,
                                              __hip_bfloat16* __restrict__ hs,
                                              float* __restrict__ base, int n) {
    const int KP = K + 8;                   // padded row (shorts)
    __shared__ unsigned short sXh[64 * KP];
    __shared__ unsigned short sXl[LO ? 64 * KP : 1];
    __shared__ unsigned short sW[128 * KP];
    int f32 = *dflag;
    int xf32 = XFLAG ? f32 : 1;
    int tid = threadIdx.x;
    int row0 = blockIdx.x * 64;

    {
        const uint4* src = (const uint4*)wt;
        uint4* dst = (uint4*)sW;
        const int C = K / 8;
        const int CP = KP / 8;
        for (int i = tid; i < 128 * C; i += 256) {
            int nrow = i / C, c = i % C;
            dst[nrow * CP + c] = src[i];
        }
    }
    for (int i = tid; i < 64 * K; i += 256) {
        int r = i / K, k = i - r * K;
        int gr = row0 + r;
        float v = (gr < n) ? ldf(xin, (size_t)gr * K + k, xf32) : 0.f;
        unsigned short h = f2bf(v);
        sXh[r * KP + k] = h;
        if (LO) sXl[r * KP + k] = f2bf(v - bf2f(h));
    }
    __syncthreads();

    int w = tid >> 6, lane = tid & 63;
    int m = lane & 15, q = lane >> 4;
    f32x4 acc[8];
#pragma unroll
    for (int ct = 0; ct < 8; ct++) acc[ct] = (f32x4){0.f, 0.f, 0.f, 0.f};

    int arow = w * 16 + m;
#pragma unroll
    for (int ks = 0; ks < K / 32; ks++) {
        int ka = ks * 32 + q * 8;
        bf16x8 ah = *(const bf16x8*)&sXh[arow * KP + ka];
        bf16x8 al;
        if (LO) al = *(const bf16x8*)&sXl[arow * KP + ka];
#pragma unroll
        for (int ct = 0; ct < 8; ct++) {
            bf16x8 bb = *(const bf16x8*)&sW[(ct * 16 + m) * KP + ka];
            acc[ct] = __builtin_amdgcn_mfma_f32_16x16x32_bf16(ah, bb, acc[ct], 0, 0, 0);
            if (LO) acc[ct] = __builtin_amdgcn_mfma_f32_16x16x32_bf16(al, bb, acc[ct], 0, 0, 0);
        }
    }

#pragma unroll
    for (int ct = 0; ct < 4; ct++) {
        int col = ct * 16 + m;
#pragma unroll
        for (int reg = 0; reg < 4; reg++) {
            int r = row0 + w * 16 + q * 4 + reg;
            if (r < n) {
                float dv = dis[r];
                float h = acc[ct][reg] * dv;
                hs[(size_t)r * 64 + col] = __float2bfloat16(h);
                base[(size_t)r * 64 + col] = h * dv + acc[ct + 4][reg] + bcat[col];
            }
        }
    }
}

// ---------------- gather-aggregate + layernorm (+relu) [+fused readout] ----------------
template <bool FINAL>
__global__ __launch_bounds__(256) void k_agg_ln(const __hip_bfloat16* __restrict__ hs,
                                                const float* __restrict__ base,
                                                const float* __restrict__ dis,
                                                const int* __restrict__ offs,
                                                const int* __restrict__ csr,
                                                const void* __restrict__ gam,
                                                const void* __restrict__ bet,
                                                const int* __restrict__ dflag,
                                                float* __restrict__ xout, int n, int relu,
                                                const int* __restrict__ batch,
                                                const void* __restrict__ lw,
                                                float* __restrict__ gsum) {
    __shared__ float sG[FINAL ? NGRAPH : 1];
    int f32 = *dflag;
    int t = threadIdx.x;
    if (FINAL) {
        if (t < NGRAPH) sG[t] = 0.f;
        __syncthreads();
    }
    int wave = t >> 6;
    int lane = t & 63;
    int v = blockIdx.x * 4 + wave;
    if (!FINAL && v >= n) return;
    if (v < n) {
        int s = offs[v];
        int e2 = offs[v + 1];
        float acc = 0.f;
        for (int i = s; i < e2; i++) {
            int src = csr[i];
            acc += __bfloat162float(hs[(size_t)src * 64 + lane]);
        }
        acc = base[(size_t)v * 64 + lane] + dis[v] * acc;
        float m = acc;
#pragma unroll
        for (int o = 32; o > 0; o >>= 1) m += __shfl_xor(m, o, 64);
        m *= (1.f / 64.f);
        float d = acc - m;
        float var = d * d;
#pragma unroll
        for (int o = 32; o > 0; o >>= 1) var += __shfl_xor(var, o, 64);
        var *= (1.f / 64.f);
        float rs = rsqrtf(var + 1e-5f);
        float y = d * rs * ldf(gam, lane, f32) + ldf(bet, lane, f32);
        if (relu) y = fmaxf(y, 0.f);
        if (!FINAL) {
            xout[(size_t)v * 64 + lane] = y;
        } else {
            float val = y * ldf(lw, lane, f32);
#pragma unroll
            for (int o = 32; o > 0; o >>= 1) val += __shfl_xor(val, o, 64);
            if (lane == 0) atomicAdd(&sG[batch[v]], val);
        }
    }
    if (FINAL) {
        __syncthreads();
        if (t < NGRAPH && sG[t] != 0.f) atomicAdd(&gsum[t], sG[t]);
    }
}

// ---------------- finalize ----------------
__global__ void k_final(const float* __restrict__ gsum, const int* __restrict__ gcnt,
                        const void* __restrict__ lb, const int* __restrict__ dflag,
                        void* __restrict__ out, int g) {
    int f32 = *dflag;
    int i = threadIdx.x;
    if (i < g) {
        float c = fmaxf((float)gcnt[i], 1.f);
        float v = gsum[i] / c + ldf(lb, 0, f32);
        if (f32) ((float*)out)[i] = v;
        else ((__hip_bfloat16*)out)[i] = __float2bfloat16(v);
    }
}

extern "C" void kernel_launch(void* const* d_in, const int* in_sizes, int n_in,
                              void* d_out, int out_size, void* d_ws, size_t ws_size,
                              hipStream_t stream) {
    const void* x_in = d_in[0];
    const int* edge_index = (const int*)d_in[1];
    const int* batch = (const int*)d_in[2];
    const void *W0 = d_in[3], *b0 = d_in[4], *W1 = d_in[5], *b1 = d_in[6],
               *W2 = d_in[7], *b2 = d_in[8];
    const void *RW0 = d_in[9], *rb0 = d_in[10], *RW1 = d_in[11], *rb1 = d_in[12],
               *RW2 = d_in[13], *rb2 = d_in[14];
    const void *g0 = d_in[15], *be0 = d_in[16], *g1 = d_in[17], *be1 = d_in[18],
               *g2 = d_in[19], *be2 = d_in[20], *lw = d_in[21], *lb = d_in[22];

    const int N = in_sizes[2];
    const int E = in_sizes[1] / 2;
    const int* erow = edge_index;
    const int* ecol = edge_index + E;

    // workspace carve (~37 MB)
    char* p = (char*)d_ws;
    size_t off = 0;
    float* dis = (float*)(p + off);  off = align256(off + (size_t)N * 4);
    int* cdeg = (int*)(p + off);     off = align256(off + (size_t)N * 4);
    int* offs = (int*)(p + off);     off = align256(off + (size_t)(N + 1) * 4);
    int* csr = (int*)(p + off);      off = align256(off + (size_t)E * 4);
    __hip_bfloat16* hs = (__hip_bfloat16*)(p + off); off = align256(off + (size_t)N * HID * 2);
    float* base = (float*)(p + off); off = align256(off + (size_t)N * HID * 4);
    float* xbuf = (float*)(p + off); off = align256(off + (size_t)N * HID * 4);
    unsigned short* wt0 = (unsigned short*)(p + off); off = align256(off + 16384 * 2);
    unsigned short* wt1 = (unsigned short*)(p + off); off = align256(off + 8192 * 2);
    unsigned short* wt2 = (unsigned short*)(p + off); off = align256(off + 8192 * 2);
    float* bcat = (float*)(p + off); off = align256(off + 192 * 4);
    int* bsum = (int*)(p + off);     off = align256(off + 256 * 4);
    int* bscan = (int*)(p + off);    off = align256(off + 256 * 4);
    float* gsum = (float*)(p + off); off = align256(off + NGRAPH * 4);
    int* gcnt = (int*)(p + off);     off = align256(off + NGRAPH * 4);
    int* dflag = (int*)(p + off);    off = align256(off + 4);
    (void)ws_size;

    const int TB = 256;
    int nb_n = (N + TB - 1) / TB;
    int nb1 = (N + 1023) / 1024;
    int nb_own = (N + RPB - 1) / RPB;
    int nb_gemm = (N + 63) / 64;
    int nb_node4 = (N + 3) / 4;

    k_sniff<<<1, 256, 0, stream>>>((const unsigned short*)x_in, 8192, dflag, gsum, gcnt);
    k_gcnt<<<nb_n, TB, 0, stream>>>(batch, gcnt, N);
    k_pack<<<130, TB, 0, stream>>>(W0, RW0, b0, rb0, W1, RW1, b1, rb1, W2, RW2, b2, rb2,
                                   dflag, wt0, wt1, wt2, bcat);
    k_count<<<nb_own, 1024, 0, stream>>>(ecol, cdeg, E, N);
    k_scan1<<<nb1, TB, 0, stream>>>(cdeg, bsum, N);
    k_scan2<<<1, TB, 0, stream>>>(bsum, bscan, offs, nb1, N);
    k_scan3<<<nb1, TB, 0, stream>>>(cdeg, bscan, offs, dis, N);
    k_fillown<<<nb_own, 1024, 0, stream>>>(erow, ecol, offs, csr, E, N);

    // layer 0 (K=128, x dtype per flag)
    k_gemm<128, true, false><<<nb_gemm, TB, 0, stream>>>(x_in, wt0, bcat, dis, dflag, hs, base, N);
    k_agg_ln<false><<<nb_node4, TB, 0, stream>>>(hs, base, dis, offs, csr, g0, be0, dflag,
                                                 xbuf, N, 1, nullptr, nullptr, nullptr);
    // layer 1 (K=64, fp32 x, hi/lo split)
    k_gemm<64, false, true><<<nb_gemm, TB, 0, stream>>>(xbuf, wt1, bcat + 64, dis, dflag, hs, base, N);
    k_agg_ln<false><<<nb_node4, TB, 0, stream>>>(hs, base, dis, offs, csr, g1, be1, dflag,
                                                 xbuf, N, 1, nullptr, nullptr, nullptr);
    // layer 2 (no relu, fused readout)
    k_gemm<64, false, true><<<nb_gemm, TB, 0, stream>>>(xbuf, wt2, bcat + 128, dis, dflag, hs, base, N);
    k_agg_ln<true><<<nb_node4, TB, 0, stream>>>(hs, base, dis, offs, csr, g2, be2, dflag,
                                                nullptr, N, 0, batch, lw, gsum);

    k_final<<<1, 64, 0, stream>>>(gsum, gcnt, lb, dflag, d_out, NGRAPH);
}

// Round 5
// 526.401 us; speedup vs baseline: 1.5634x; 1.4101x over previous
//
#include <hip/hip_runtime.h>
#include <hip/hip_bf16.h>

#define HID 64
#define NGRAPH 64
#define BSH 7            // bucket = 128 nodes
#define NCH 384          // edge chunks for hist/scatter

static inline size_t align256(size_t x) { return (x + 255) & ~(size_t)255; }

typedef __attribute__((ext_vector_type(8))) short bf16x8;
typedef __attribute__((ext_vector_type(4))) float f32x4;

// ---- dtype-agnostic float load: f32 ? fp32[i] : bf16[i] ----
__device__ __forceinline__ float ldf(const void* p, size_t i, int f32) {
    if (f32) return ((const float*)p)[i];
    unsigned int w = ((unsigned int)((const unsigned short*)p)[i]) << 16;
    return __uint_as_float(w);
}
__device__ __forceinline__ float bf2f(unsigned short u) {
    return __uint_as_float(((unsigned int)u) << 16);
}
__device__ __forceinline__ unsigned short f2bf(float f) {
    __hip_bfloat16 h = __float2bfloat16(f);
    return *(unsigned short*)&h;
}

// ---------------- dtype sniffer + zero small accumulators ----------------
__global__ void k_sniff(const unsigned short* __restrict__ x, int nwords, int* __restrict__ flag,
                        float* __restrict__ gsum, int* __restrict__ gcnt) {
    __shared__ int cw, cz;
    int t = threadIdx.x;
    if (t == 0) { cw = 0; cz = 0; }
    if (t < NGRAPH) { gsum[t] = 0.f; gcnt[t] = 0; }
    __syncthreads();
    int weird = 0, evenzero = 0;
    for (int i = t; i < nwords; i += blockDim.x) {
        unsigned short u = x[i];
        int e = (u >> 7) & 0xFF;
        if (e >= 128) weird++;
        if (((i & 1) == 0) && ((u & 0x7FFF) == 0)) evenzero++;
    }
    atomicAdd(&cw, weird);
    atomicAdd(&cz, evenzero);
    __syncthreads();
    if (t == 0) *flag = (cw > nwords / 16 || cz > nwords / 8) ? 1 : 0;
}

// ---------------- per-graph node counts ----------------
__global__ void k_gcnt(const int* __restrict__ batch, int* __restrict__ gcnt, int n) {
    __shared__ int h[NGRAPH];
    int t = threadIdx.x;
    if (t < NGRAPH) h[t] = 0;
    __syncthreads();
    int i = blockIdx.x * blockDim.x + t;
    if (i < n) atomicAdd(&h[batch[i]], 1);
    __syncthreads();
    if (t < NGRAPH && h[t] > 0) atomicAdd(&gcnt[t], h[t]);
}

// ---------------- weight pack ----------------
__global__ void k_pack(const void* W0, const void* RW0, const void* b0, const void* rb0,
                       const void* W1, const void* RW1, const void* b1, const void* rb1,
                       const void* W2, const void* RW2, const void* b2, const void* rb2,
                       const int* __restrict__ dflag,
                       unsigned short* wt0, unsigned short* wt1, unsigned short* wt2,
                       float* bcat) {
    int f = *dflag;
    int i = blockIdx.x * blockDim.x + threadIdx.x;
    if (i < 16384) {
        int n = i >> 7, k = i & 127;
        float v = (n < 64) ? ldf(W0, (size_t)k * 64 + n, f) : ldf(RW0, (size_t)k * 64 + (n - 64), f);
        wt0[n * 128 + k] = f2bf(v);
    } else if (i < 24576) {
        int j = i - 16384; int n = j >> 6, k = j & 63;
        float v = (n < 64) ? ldf(W1, (size_t)k * 64 + n, f) : ldf(RW1, (size_t)k * 64 + (n - 64), f);
        wt1[n * 64 + k] = f2bf(v);
    } else if (i < 32768) {
        int j = i - 24576; int n = j >> 6, k = j & 63;
        float v = (n < 64) ? ldf(W2, (size_t)k * 64 + n, f) : ldf(RW2, (size_t)k * 64 + (n - 64), f);
        wt2[n * 64 + k] = f2bf(v);
    } else if (i < 32768 + 192) {
        int j = i - 32768; int l = j >> 6, c = j & 63;
        const void* bb = (l == 0) ? b0 : (l == 1) ? b1 : b2;
        const void* rr = (l == 0) ? rb0 : (l == 1) ? rb1 : rb2;
        bcat[l * 64 + c] = ldf(bb, c, f) + ldf(rr, c, f);
    }
}

// ---------------- bucket histogram: hist[bucket][chunk], edge-parallel ----------------
__global__ __launch_bounds__(256) void k_hist(const int* __restrict__ ecol, int e, int nbuck,
                                              int* __restrict__ hist) {
    __shared__ int sh[1024];
    int c = blockIdx.x, t = threadIdx.x;
    for (int i = t; i < nbuck; i += 256) sh[i] = 0;
    __syncthreads();
    int per = (e + NCH - 1) / NCH;
    int s = c * per, en = min(e, s + per);
    for (int i = s + t; i < en; i += 256)
        atomicAdd(&sh[ecol[i] >> BSH], 1);
    __syncthreads();
    for (int i = t; i < nbuck; i += 256) hist[i * NCH + c] = sh[i];
}

// ---------------- hierarchical scan (generic, 1024 elems/block) ----------------
__global__ void k_scan1(const int* __restrict__ src, int* __restrict__ bsum, int n) {
    __shared__ int s[256];
    int t = threadIdx.x;
    int base = blockIdx.x * 1024 + t * 4;
    int sum = 0;
#pragma unroll
    for (int j = 0; j < 4; j++) { int i = base + j; if (i < n) sum += src[i]; }
    s[t] = sum;
    __syncthreads();
    for (int o = 128; o > 0; o >>= 1) {
        if (t < o) s[t] += s[t + o];
        __syncthreads();
    }
    if (t == 0) bsum[blockIdx.x] = s[0];
}

__global__ void k_scan2(const int* __restrict__ bsum, int* __restrict__ bscan,
                        int* __restrict__ out, int nb, int n) {
    __shared__ int s[256];
    int t = threadIdx.x;
    int v = (t < nb) ? bsum[t] : 0;
    s[t] = v;
    __syncthreads();
    for (int o = 1; o < 256; o <<= 1) {
        int x = (t >= o) ? s[t - o] : 0;
        __syncthreads();
        s[t] += x;
        __syncthreads();
    }
    if (t < nb) bscan[t] = s[t] - v;        // exclusive
    if (t == nb - 1) out[n] = s[t];         // total
}

__global__ void k_scan3(const int* __restrict__ src, const int* __restrict__ bscan,
                        int* __restrict__ out, int n) {
    __shared__ int s[256];
    int t = threadIdx.x;
    int base = blockIdx.x * 1024 + t * 4;
    int tsum = 0;
#pragma unroll
    for (int j = 0; j < 4; j++) { int i = base + j; if (i < n) tsum += src[i]; }
    s[t] = tsum;
    __syncthreads();
    for (int o = 1; o < 256; o <<= 1) {
        int x = (t >= o) ? s[t - o] : 0;
        __syncthreads();
        s[t] += x;
        __syncthreads();
    }
    int off = bscan[blockIdx.x] + s[t] - tsum;
#pragma unroll
    for (int j = 0; j < 4; j++) {
        int i = base + j;
        if (i < n) { out[i] = off; off += src[i]; }
    }
}

// ---------------- bucket scatter: ebuf[pos] = (src, tgt), bucket-contiguous ----------------
__global__ __launch_bounds__(256) void k_scatter(const int* __restrict__ erow,
                                                 const int* __restrict__ ecol, int e, int nbuck,
                                                 const int* __restrict__ hoffs,
                                                 int2* __restrict__ ebuf) {
    __shared__ int cur[1024];
    int c = blockIdx.x, t = threadIdx.x;
    for (int i = t; i < nbuck; i += 256) cur[i] = hoffs[i * NCH + c];
    __syncthreads();
    int per = (e + NCH - 1) / NCH;
    int s = c * per, en = min(e, s + per);
    for (int i = s + t; i < en; i += 256) {
        int tg = ecol[i];
        int p = atomicAdd(&cur[tg >> BSH], 1);
        ebuf[p] = make_int2(erow[i], tg);
    }
}

// ---------------- per-bucket: degree hist + local scan -> offs/dis, then CSR fill ----------------
__global__ __launch_bounds__(256) void k_bucket(const int2* __restrict__ ebuf,
                                                const int* __restrict__ hoffs,
                                                int nbuck, int n, int e,
                                                int* __restrict__ offs, float* __restrict__ dis,
                                                int* __restrict__ csr) {
    __shared__ int hist[128];
    __shared__ int lofs[128];
    __shared__ int curs[128];
    int b = blockIdx.x, t = threadIdx.x;
    int nb0 = b << BSH;
    int nn = n - nb0; if (nn > 128) nn = 128;
    int s = hoffs[b * NCH];
    int en = (b + 1 < nbuck) ? hoffs[(b + 1) * NCH] : e;
    if (t < 128) hist[t] = 0;
    __syncthreads();
    for (int i = s + t; i < en; i += 256)
        atomicAdd(&hist[ebuf[i].y & 127], 1);
    __syncthreads();
    if (t < 128) lofs[t] = hist[t];
    __syncthreads();
    for (int o = 1; o < 128; o <<= 1) {
        int v = (t < 128 && t >= o) ? lofs[t - o] : 0;
        __syncthreads();
        if (t < 128) lofs[t] += v;          // inclusive scan
        __syncthreads();
    }
    if (t < nn) {
        int ex = s + lofs[t] - hist[t];     // bucket base + local exclusive
        offs[nb0 + t] = ex;
        curs[t] = ex;
        dis[nb0 + t] = rsqrtf((float)(hist[t] + 1));
    }
    if (b == nbuck - 1 && t == 0) offs[n] = e;
    __syncthreads();
    for (int i = s + t; i < en; i += 256) {
        int2 ed = ebuf[i];
        int p = atomicAdd(&curs[ed.y & 127], 1);
        csr[p] = ed.x;
    }
}

// ---------------- MFMA dual GEMM (unchanged) ----------------
template <int K, bool XFLAG, bool LO>
__global__ __launch_bounds__(256) void k_gemm(const void* __restrict__ xin,
                                              const unsigned short* __restrict__ wt,
                                              const float* __restrict__ bcat,
                                              const float* __restrict__ dis,
                                              const int* __restrict__ dflag,
                                              __hip_bfloat16* __restrict__ hs,
                                              float* __restrict__ base, int n) {
    const int KP = K + 8;
    __shared__ unsigned short sXh[64 * KP];
    __shared__ unsigned short sXl[LO ? 64 * KP : 1];
    __shared__ unsigned short sW[128 * KP];
    int f32 = *dflag;
    int xf32 = XFLAG ? f32 : 1;
    int tid = threadIdx.x;
    int row0 = blockIdx.x * 64;

    {
        const uint4* src = (const uint4*)wt;
        uint4* dst = (uint4*)sW;
        const int C = K / 8;
        const int CP = KP / 8;
        for (int i = tid; i < 128 * C; i += 256) {
            int nrow = i / C, c = i % C;
            dst[nrow * CP + c] = src[i];
        }
    }
    for (int i = tid; i < 64 * K; i += 256) {
        int r = i / K, k = i - r * K;
        int gr = row0 + r;
        float v = (gr < n) ? ldf(xin, (size_t)gr * K + k, xf32) : 0.f;
        unsigned short h = f2bf(v);
        sXh[r * KP + k] = h;
        if (LO) sXl[r * KP + k] = f2bf(v - bf2f(h));
    }
    __syncthreads();

    int w = tid >> 6, lane = tid & 63;
    int m = lane & 15, q = lane >> 4;
    f32x4 acc[8];
#pragma unroll
    for (int ct = 0; ct < 8; ct++) acc[ct] = (f32x4){0.f, 0.f, 0.f, 0.f};

    int arow = w * 16 + m;
#pragma unroll
    for (int ks = 0; ks < K / 32; ks++) {
        int ka = ks * 32 + q * 8;
        bf16x8 ah = *(const bf16x8*)&sXh[arow * KP + ka];
        bf16x8 al;
        if (LO) al = *(const bf16x8*)&sXl[arow * KP + ka];
#pragma unroll
        for (int ct = 0; ct < 8; ct++) {
            bf16x8 bb = *(const bf16x8*)&sW[(ct * 16 + m) * KP + ka];
            acc[ct] = __builtin_amdgcn_mfma_f32_16x16x32_bf16(ah, bb, acc[ct], 0, 0, 0);
            if (LO) acc[ct] = __builtin_amdgcn_mfma_f32_16x16x32_bf16(al, bb, acc[ct], 0, 0, 0);
        }
    }

#pragma unroll
    for (int ct = 0; ct < 4; ct++) {
        int col = ct * 16 + m;
#pragma unroll
        for (int reg = 0; reg < 4; reg++) {
            int r = row0 + w * 16 + q * 4 + reg;
            if (r < n) {
                float dv = dis[r];
                float h = acc[ct][reg] * dv;
                hs[(size_t)r * 64 + col] = __float2bfloat16(h);
                base[(size_t)r * 64 + col] = h * dv + acc[ct + 4][reg] + bcat[col];
            }
        }
    }
}

// ---------------- gather-aggregate + layernorm (+relu) [+fused readout] ----------------
template <bool FINAL>
__global__ __launch_bounds__(256) void k_agg_ln(const __hip_bfloat16* __restrict__ hs,
                                                const float* __restrict__ base,
                                                const float* __restrict__ dis,
                                                const int* __restrict__ offs,
                                                const int* __restrict__ csr,
                                                const void* __restrict__ gam,
                                                const void* __restrict__ bet,
                                                const int* __restrict__ dflag,
                                                float* __restrict__ xout, int n, int relu,
                                                const int* __restrict__ batch,
                                                const void* __restrict__ lw,
                                                float* __restrict__ gsum) {
    __shared__ float sG[FINAL ? NGRAPH : 1];
    int f32 = *dflag;
    int t = threadIdx.x;
    if (FINAL) {
        if (t < NGRAPH) sG[t] = 0.f;
        __syncthreads();
    }
    int wave = t >> 6;
    int lane = t & 63;
    int v = blockIdx.x * 4 + wave;
    if (!FINAL && v >= n) return;
    if (v < n) {
        int s = offs[v];
        int e2 = offs[v + 1];
        float acc = 0.f;
        for (int i = s; i < e2; i++) {
            int src = csr[i];
            acc += __bfloat162float(hs[(size_t)src * 64 + lane]);
        }
        acc = base[(size_t)v * 64 + lane] + dis[v] * acc;
        float m = acc;
#pragma unroll
        for (int o = 32; o > 0; o >>= 1) m += __shfl_xor(m, o, 64);
        m *= (1.f / 64.f);
        float d = acc - m;
        float var = d * d;
#pragma unroll
        for (int o = 32; o > 0; o >>= 1) var += __shfl_xor(var, o, 64);
        var *= (1.f / 64.f);
        float rs = rsqrtf(var + 1e-5f);
        float y = d * rs * ldf(gam, lane, f32) + ldf(bet, lane, f32);
        if (relu) y = fmaxf(y, 0.f);
        if (!FINAL) {
            xout[(size_t)v * 64 + lane] = y;
        } else {
            float val = y * ldf(lw, lane, f32);
#pragma unroll
            for (int o = 32; o > 0; o >>= 1) val += __shfl_xor(val, o, 64);
            if (lane == 0) atomicAdd(&sG[batch[v]], val);
        }
    }
    if (FINAL) {
        __syncthreads();
        if (t < NGRAPH && sG[t] != 0.f) atomicAdd(&gsum[t], sG[t]);
    }
}

// ---------------- finalize ----------------
__global__ void k_final(const float* __restrict__ gsum, const int* __restrict__ gcnt,
                        const void* __restrict__ lb, const int* __restrict__ dflag,
                        void* __restrict__ out, int g) {
    int f32 = *dflag;
    int i = threadIdx.x;
    if (i < g) {
        float c = fmaxf((float)gcnt[i], 1.f);
        float v = gsum[i] / c + ldf(lb, 0, f32);
        if (f32) ((float*)out)[i] = v;
        else ((__hip_bfloat16*)out)[i] = __float2bfloat16(v);
    }
}

extern "C" void kernel_launch(void* const* d_in, const int* in_sizes, int n_in,
                              void* d_out, int out_size, void* d_ws, size_t ws_size,
                              hipStream_t stream) {
    const void* x_in = d_in[0];
    const int* edge_index = (const int*)d_in[1];
    const int* batch = (const int*)d_in[2];
    const void *W0 = d_in[3], *b0 = d_in[4], *W1 = d_in[5], *b1 = d_in[6],
               *W2 = d_in[7], *b2 = d_in[8];
    const void *RW0 = d_in[9], *rb0 = d_in[10], *RW1 = d_in[11], *rb1 = d_in[12],
               *RW2 = d_in[13], *rb2 = d_in[14];
    const void *g0 = d_in[15], *be0 = d_in[16], *g1 = d_in[17], *be1 = d_in[18],
               *g2 = d_in[19], *be2 = d_in[20], *lw = d_in[21], *lb = d_in[22];

    const int N = in_sizes[2];
    const int E = in_sizes[1] / 2;
    const int* erow = edge_index;
    const int* ecol = edge_index + E;
    const int nbuck = (N + 127) >> BSH;
    const int T = nbuck * NCH;               // histogram entries

    // workspace carve (~45 MB)
    char* p = (char*)d_ws;
    size_t off = 0;
    float* dis = (float*)(p + off);  off = align256(off + (size_t)N * 4);
    int* offs = (int*)(p + off);     off = align256(off + (size_t)(N + 1) * 4);
    int* csr = (int*)(p + off);      off = align256(off + (size_t)E * 4);
    int2* ebuf = (int2*)(p + off);   off = align256(off + (size_t)E * 8);
    int* hist = (int*)(p + off);     off = align256(off + (size_t)T * 4);
    int* hoffs = (int*)(p + off);    off = align256(off + (size_t)(T + 1) * 4);
    __hip_bfloat16* hs = (__hip_bfloat16*)(p + off); off = align256(off + (size_t)N * HID * 2);
    float* base = (float*)(p + off); off = align256(off + (size_t)N * HID * 4);
    float* xbuf = (float*)(p + off); off = align256(off + (size_t)N * HID * 4);
    unsigned short* wt0 = (unsigned short*)(p + off); off = align256(off + 16384 * 2);
    unsigned short* wt1 = (unsigned short*)(p + off); off = align256(off + 8192 * 2);
    unsigned short* wt2 = (unsigned short*)(p + off); off = align256(off + 8192 * 2);
    float* bcat = (float*)(p + off); off = align256(off + 192 * 4);
    int* bsum = (int*)(p + off);     off = align256(off + 256 * 4);
    int* bscan = (int*)(p + off);    off = align256(off + 256 * 4);
    float* gsum = (float*)(p + off); off = align256(off + NGRAPH * 4);
    int* gcnt = (int*)(p + off);     off = align256(off + NGRAPH * 4);
    int* dflag = (int*)(p + off);    off = align256(off + 4);
    (void)ws_size;

    const int TB = 256;
    int nb_n = (N + TB - 1) / TB;
    int nbT = (T + 1023) / 1024;             // scan blocks over histogram
    int nb_gemm = (N + 63) / 64;
    int nb_node4 = (N + 3) / 4;

    k_sniff<<<1, 256, 0, stream>>>((const unsigned short*)x_in, 8192, dflag, gsum, gcnt);
    k_gcnt<<<nb_n, TB, 0, stream>>>(batch, gcnt, N);
    k_pack<<<130, TB, 0, stream>>>(W0, RW0, b0, rb0, W1, RW1, b1, rb1, W2, RW2, b2, rb2,
                                   dflag, wt0, wt1, wt2, bcat);
    // bucketed CSR build: O(E) per pass, all atomics in LDS
    k_hist<<<NCH, TB, 0, stream>>>(ecol, E, nbuck, hist);
    k_scan1<<<nbT, TB, 0, stream>>>(hist, bsum, T);
    k_scan2<<<1, TB, 0, stream>>>(bsum, bscan, hoffs, nbT, T);
    k_scan3<<<nbT, TB, 0, stream>>>(hist, bscan, hoffs, T);
    k_scatter<<<NCH, TB, 0, stream>>>(erow, ecol, E, nbuck, hoffs, ebuf);
    k_bucket<<<nbuck, TB, 0, stream>>>(ebuf, hoffs, nbuck, N, E, offs, dis, csr);

    // layer 0 (K=128, x dtype per flag)
    k_gemm<128, true, false><<<nb_gemm, TB, 0, stream>>>(x_in, wt0, bcat, dis, dflag, hs, base, N);
    k_agg_ln<false><<<nb_node4, TB, 0, stream>>>(hs, base, dis, offs, csr, g0, be0, dflag,
                                                 xbuf, N, 1, nullptr, nullptr, nullptr);
    // layer 1 (K=64, fp32 x, hi/lo split)
    k_gemm<64, false, true><<<nb_gemm, TB, 0, stream>>>(xbuf, wt1, bcat + 64, dis, dflag, hs, base, N);
    k_agg_ln<false><<<nb_node4, TB, 0, stream>>>(hs, base, dis, offs, csr, g1, be1, dflag,
                                                 xbuf, N, 1, nullptr, nullptr, nullptr);
    // layer 2 (no relu, fused readout)
    k_gemm<64, false, true><<<nb_gemm, TB, 0, stream>>>(xbuf, wt2, bcat + 128, dis, dflag, hs, base, N);
    k_agg_ln<true><<<nb_node4, TB, 0, stream>>>(hs, base, dis, offs, csr, g2, be2, dflag,
                                                nullptr, N, 0, batch, lw, gsum);

    k_final<<<1, 64, 0, stream>>>(gsum, gcnt, lb, dflag, d_out, NGRAPH);
}

// Round 6
// 430.094 us; speedup vs baseline: 1.9135x; 1.2239x over previous
//
#include <hip/hip_runtime.h>
#include <hip/hip_bf16.h>

#define HID 64
#define NGRAPH 64
#define BSH 7            // bucket = 128 nodes
#define NCH 384          // edge chunks for hist/scatter

static inline size_t align256(size_t x) { return (x + 255) & ~(size_t)255; }

typedef __attribute__((ext_vector_type(8))) short bf16x8;
typedef __attribute__((ext_vector_type(4))) float f32x4;

// ---- dtype-agnostic float load: f32 ? fp32[i] : bf16[i] ----
__device__ __forceinline__ float ldf(const void* p, size_t i, int f32) {
    if (f32) return ((const float*)p)[i];
    unsigned int w = ((unsigned int)((const unsigned short*)p)[i]) << 16;
    return __uint_as_float(w);
}
__device__ __forceinline__ float bf2f(unsigned short u) {
    return __uint_as_float(((unsigned int)u) << 16);
}
__device__ __forceinline__ unsigned short f2bf(float f) {
    __hip_bfloat16 h = __float2bfloat16(f);
    return *(unsigned short*)&h;
}

// ---------------- dtype sniffer + zero small accumulators ----------------
__global__ void k_sniff(const unsigned short* __restrict__ x, int nwords, int* __restrict__ flag,
                        float* __restrict__ gsum, int* __restrict__ gcnt) {
    __shared__ int cw, cz;
    int t = threadIdx.x;
    if (t == 0) { cw = 0; cz = 0; }
    if (t < NGRAPH) { gsum[t] = 0.f; gcnt[t] = 0; }
    __syncthreads();
    int weird = 0, evenzero = 0;
    for (int i = t; i < nwords; i += blockDim.x) {
        unsigned short u = x[i];
        int e = (u >> 7) & 0xFF;
        if (e >= 128) weird++;
        if (((i & 1) == 0) && ((u & 0x7FFF) == 0)) evenzero++;
    }
    atomicAdd(&cw, weird);
    atomicAdd(&cz, evenzero);
    __syncthreads();
    if (t == 0) *flag = (cw > nwords / 16 || cz > nwords / 8) ? 1 : 0;
}

// ---------------- per-graph node counts ----------------
__global__ void k_gcnt(const int* __restrict__ batch, int* __restrict__ gcnt, int n) {
    __shared__ int h[NGRAPH];
    int t = threadIdx.x;
    if (t < NGRAPH) h[t] = 0;
    __syncthreads();
    int i = blockIdx.x * blockDim.x + t;
    if (i < n) atomicAdd(&h[batch[i]], 1);
    __syncthreads();
    if (t < NGRAPH && h[t] > 0) atomicAdd(&gcnt[t], h[t]);
}

// ---------------- weight pack ----------------
__global__ void k_pack(const void* W0, const void* RW0, const void* b0, const void* rb0,
                       const void* W1, const void* RW1, const void* b1, const void* rb1,
                       const void* W2, const void* RW2, const void* b2, const void* rb2,
                       const int* __restrict__ dflag,
                       unsigned short* wt0, unsigned short* wt1, unsigned short* wt2,
                       float* bcat) {
    int f = *dflag;
    int i = blockIdx.x * blockDim.x + threadIdx.x;
    if (i < 16384) {
        int n = i >> 7, k = i & 127;
        float v = (n < 64) ? ldf(W0, (size_t)k * 64 + n, f) : ldf(RW0, (size_t)k * 64 + (n - 64), f);
        wt0[n * 128 + k] = f2bf(v);
    } else if (i < 24576) {
        int j = i - 16384; int n = j >> 6, k = j & 63;
        float v = (n < 64) ? ldf(W1, (size_t)k * 64 + n, f) : ldf(RW1, (size_t)k * 64 + (n - 64), f);
        wt1[n * 64 + k] = f2bf(v);
    } else if (i < 32768) {
        int j = i - 24576; int n = j >> 6, k = j & 63;
        float v = (n < 64) ? ldf(W2, (size_t)k * 64 + n, f) : ldf(RW2, (size_t)k * 64 + (n - 64), f);
        wt2[n * 64 + k] = f2bf(v);
    } else if (i < 32768 + 192) {
        int j = i - 32768; int l = j >> 6, c = j & 63;
        const void* bb = (l == 0) ? b0 : (l == 1) ? b1 : b2;
        const void* rr = (l == 0) ? rb0 : (l == 1) ? rb1 : rb2;
        bcat[l * 64 + c] = ldf(bb, c, f) + ldf(rr, c, f);
    }
}

// ---------------- bucket histogram: hist[bucket][chunk], edge-parallel ----------------
__global__ __launch_bounds__(256) void k_hist(const int* __restrict__ ecol, int e, int nbuck,
                                              int* __restrict__ hist) {
    __shared__ int sh[1024];
    int c = blockIdx.x, t = threadIdx.x;
    for (int i = t; i < nbuck; i += 256) sh[i] = 0;
    __syncthreads();
    int per = (e + NCH - 1) / NCH;
    int s = c * per, en = min(e, s + per);
    for (int i = s + t; i < en; i += 256)
        atomicAdd(&sh[ecol[i] >> BSH], 1);
    __syncthreads();
    for (int i = t; i < nbuck; i += 256) hist[i * NCH + c] = sh[i];
}

// ---------------- hierarchical scan (generic, 1024 elems/block) ----------------
__global__ void k_scan1(const int* __restrict__ src, int* __restrict__ bsum, int n) {
    __shared__ int s[256];
    int t = threadIdx.x;
    int base = blockIdx.x * 1024 + t * 4;
    int sum = 0;
#pragma unroll
    for (int j = 0; j < 4; j++) { int i = base + j; if (i < n) sum += src[i]; }
    s[t] = sum;
    __syncthreads();
    for (int o = 128; o > 0; o >>= 1) {
        if (t < o) s[t] += s[t + o];
        __syncthreads();
    }
    if (t == 0) bsum[blockIdx.x] = s[0];
}

__global__ void k_scan2(const int* __restrict__ bsum, int* __restrict__ bscan,
                        int* __restrict__ out, int nb, int n) {
    __shared__ int s[256];
    int t = threadIdx.x;
    int v = (t < nb) ? bsum[t] : 0;
    s[t] = v;
    __syncthreads();
    for (int o = 1; o < 256; o <<= 1) {
        int x = (t >= o) ? s[t - o] : 0;
        __syncthreads();
        s[t] += x;
        __syncthreads();
    }
    if (t < nb) bscan[t] = s[t] - v;        // exclusive
    if (t == nb - 1) out[n] = s[t];         // total
}

__global__ void k_scan3(const int* __restrict__ src, const int* __restrict__ bscan,
                        int* __restrict__ out, int n) {
    __shared__ int s[256];
    int t = threadIdx.x;
    int base = blockIdx.x * 1024 + t * 4;
    int tsum = 0;
#pragma unroll
    for (int j = 0; j < 4; j++) { int i = base + j; if (i < n) tsum += src[i]; }
    s[t] = tsum;
    __syncthreads();
    for (int o = 1; o < 256; o <<= 1) {
        int x = (t >= o) ? s[t - o] : 0;
        __syncthreads();
        s[t] += x;
        __syncthreads();
    }
    int off = bscan[blockIdx.x] + s[t] - tsum;
#pragma unroll
    for (int j = 0; j < 4; j++) {
        int i = base + j;
        if (i < n) { out[i] = off; off += src[i]; }
    }
}

// ---------------- bucket scatter: ebuf[pos] = (src, tgt), bucket-contiguous ----------------
__global__ __launch_bounds__(256) void k_scatter(const int* __restrict__ erow,
                                                 const int* __restrict__ ecol, int e, int nbuck,
                                                 const int* __restrict__ hoffs,
                                                 int2* __restrict__ ebuf) {
    __shared__ int cur[1024];
    int c = blockIdx.x, t = threadIdx.x;
    for (int i = t; i < nbuck; i += 256) cur[i] = hoffs[i * NCH + c];
    __syncthreads();
    int per = (e + NCH - 1) / NCH;
    int s = c * per, en = min(e, s + per);
    for (int i = s + t; i < en; i += 256) {
        int tg = ecol[i];
        int p = atomicAdd(&cur[tg >> BSH], 1);
        ebuf[p] = make_int2(erow[i], tg);
    }
}

// ---------------- per-bucket: degree hist + local scan -> offs/dis, then CSR fill ----------------
__global__ __launch_bounds__(256) void k_bucket(const int2* __restrict__ ebuf,
                                                const int* __restrict__ hoffs,
                                                int nbuck, int n, int e,
                                                int* __restrict__ offs, float* __restrict__ dis,
                                                int* __restrict__ csr) {
    __shared__ int hist[128];
    __shared__ int lofs[128];
    __shared__ int curs[128];
    int b = blockIdx.x, t = threadIdx.x;
    int nb0 = b << BSH;
    int nn = n - nb0; if (nn > 128) nn = 128;
    int s = hoffs[b * NCH];
    int en = (b + 1 < nbuck) ? hoffs[(b + 1) * NCH] : e;
    if (t < 128) hist[t] = 0;
    __syncthreads();
    for (int i = s + t; i < en; i += 256)
        atomicAdd(&hist[ebuf[i].y & 127], 1);
    __syncthreads();
    if (t < 128) lofs[t] = hist[t];
    __syncthreads();
    for (int o = 1; o < 128; o <<= 1) {
        int v = (t < 128 && t >= o) ? lofs[t - o] : 0;
        __syncthreads();
        if (t < 128) lofs[t] += v;          // inclusive scan
        __syncthreads();
    }
    if (t < nn) {
        int ex = s + lofs[t] - hist[t];     // bucket base + local exclusive
        offs[nb0 + t] = ex;
        curs[t] = ex;
        dis[nb0 + t] = rsqrtf((float)(hist[t] + 1));
    }
    if (b == nbuck - 1 && t == 0) offs[n] = e;
    __syncthreads();
    for (int i = s + t; i < en; i += 256) {
        int2 ed = ebuf[i];
        int p = atomicAdd(&curs[ed.y & 127], 1);
        csr[p] = ed.x;
    }
}

// ---------------- MFMA dual GEMM (unchanged) ----------------
template <int K, bool XFLAG, bool LO>
__global__ __launch_bounds__(256) void k_gemm(const void* __restrict__ xin,
                                              const unsigned short* __restrict__ wt,
                                              const float* __restrict__ bcat,
                                              const float* __restrict__ dis,
                                              const int* __restrict__ dflag,
                                              __hip_bfloat16* __restrict__ hs,
                                              float* __restrict__ base, int n) {
    const int KP = K + 8;
    __shared__ unsigned short sXh[64 * KP];
    __shared__ unsigned short sXl[LO ? 64 * KP : 1];
    __shared__ unsigned short sW[128 * KP];
    int f32 = *dflag;
    int xf32 = XFLAG ? f32 : 1;
    int tid = threadIdx.x;
    int row0 = blockIdx.x * 64;

    {
        const uint4* src = (const uint4*)wt;
        uint4* dst = (uint4*)sW;
        const int C = K / 8;
        const int CP = KP / 8;
        for (int i = tid; i < 128 * C; i += 256) {
            int nrow = i / C, c = i % C;
            dst[nrow * CP + c] = src[i];
        }
    }
    for (int i = tid; i < 64 * K; i += 256) {
        int r = i / K, k = i - r * K;
        int gr = row0 + r;
        float v = (gr < n) ? ldf(xin, (size_t)gr * K + k, xf32) : 0.f;
        unsigned short h = f2bf(v);
        sXh[r * KP + k] = h;
        if (LO) sXl[r * KP + k] = f2bf(v - bf2f(h));
    }
    __syncthreads();

    int w = tid >> 6, lane = tid & 63;
    int m = lane & 15, q = lane >> 4;
    f32x4 acc[8];
#pragma unroll
    for (int ct = 0; ct < 8; ct++) acc[ct] = (f32x4){0.f, 0.f, 0.f, 0.f};

    int arow = w * 16 + m;
#pragma unroll
    for (int ks = 0; ks < K / 32; ks++) {
        int ka = ks * 32 + q * 8;
        bf16x8 ah = *(const bf16x8*)&sXh[arow * KP + ka];
        bf16x8 al;
        if (LO) al = *(const bf16x8*)&sXl[arow * KP + ka];
#pragma unroll
        for (int ct = 0; ct < 8; ct++) {
            bf16x8 bb = *(const bf16x8*)&sW[(ct * 16 + m) * KP + ka];
            acc[ct] = __builtin_amdgcn_mfma_f32_16x16x32_bf16(ah, bb, acc[ct], 0, 0, 0);
            if (LO) acc[ct] = __builtin_amdgcn_mfma_f32_16x16x32_bf16(al, bb, acc[ct], 0, 0, 0);
        }
    }

#pragma unroll
    for (int ct = 0; ct < 4; ct++) {
        int col = ct * 16 + m;
#pragma unroll
        for (int reg = 0; reg < 4; reg++) {
            int r = row0 + w * 16 + q * 4 + reg;
            if (r < n) {
                float dv = dis[r];
                float h = acc[ct][reg] * dv;
                hs[(size_t)r * 64 + col] = __float2bfloat16(h);
                base[(size_t)r * 64 + col] = h * dv + acc[ct + 4][reg] + bcat[col];
            }
        }
    }
}

// ---------------- gather-aggregate + layernorm (+relu) [+fused readout] ----------------
// wave per node; 4 edge-groups of 16 lanes; lane l covers features 4l..4l+3 (uint2 = 4 bf16)
template <bool FINAL>
__global__ __launch_bounds__(256) void k_agg_ln(const __hip_bfloat16* __restrict__ hs,
                                                const float* __restrict__ base,
                                                const float* __restrict__ dis,
                                                const int* __restrict__ offs,
                                                const int* __restrict__ csr,
                                                const void* __restrict__ gam,
                                                const void* __restrict__ bet,
                                                const int* __restrict__ dflag,
                                                float* __restrict__ xout, int n, int relu,
                                                const int* __restrict__ batch,
                                                const void* __restrict__ lw,
                                                float* __restrict__ gsum) {
    __shared__ float sG[FINAL ? NGRAPH : 1];
    int f32 = *dflag;
    int t = threadIdx.x;
    if (FINAL) {
        if (t < NGRAPH) sG[t] = 0.f;
        __syncthreads();
    }
    int wave = t >> 6;
    int lane = t & 63;
    int g = lane >> 4;          // edge group
    int l = lane & 15;          // feature quad
    int v = blockIdx.x * 4 + wave;
    if (!FINAL && v >= n) return;
    if (v < n) {
        int s = offs[v];
        int e2 = offs[v + 1];
        const unsigned short* hsp = (const unsigned short*)hs;
        float a0 = 0.f, a1 = 0.f, a2 = 0.f, a3 = 0.f;
        int i = s + g;
        for (; i + 4 < e2; i += 8) {                  // 2 edges per group in flight
            int s0 = csr[i];
            int s1 = csr[i + 4];
            uint2 p0 = *(const uint2*)(hsp + (size_t)s0 * 64 + l * 4);
            uint2 p1 = *(const uint2*)(hsp + (size_t)s1 * 64 + l * 4);
            a0 += bf2f((unsigned short)(p0.x & 0xFFFF)) + bf2f((unsigned short)(p1.x & 0xFFFF));
            a1 += bf2f((unsigned short)(p0.x >> 16))    + bf2f((unsigned short)(p1.x >> 16));
            a2 += bf2f((unsigned short)(p0.y & 0xFFFF)) + bf2f((unsigned short)(p1.y & 0xFFFF));
            a3 += bf2f((unsigned short)(p0.y >> 16))    + bf2f((unsigned short)(p1.y >> 16));
        }
        if (i < e2) {
            int s0 = csr[i];
            uint2 p0 = *(const uint2*)(hsp + (size_t)s0 * 64 + l * 4);
            a0 += bf2f((unsigned short)(p0.x & 0xFFFF));
            a1 += bf2f((unsigned short)(p0.x >> 16));
            a2 += bf2f((unsigned short)(p0.y & 0xFFFF));
            a3 += bf2f((unsigned short)(p0.y >> 16));
        }
        // fold the 4 edge groups (lanes with same l)
        a0 += __shfl_xor(a0, 16, 64); a0 += __shfl_xor(a0, 32, 64);
        a1 += __shfl_xor(a1, 16, 64); a1 += __shfl_xor(a1, 32, 64);
        a2 += __shfl_xor(a2, 16, 64); a2 += __shfl_xor(a2, 32, 64);
        a3 += __shfl_xor(a3, 16, 64); a3 += __shfl_xor(a3, 32, 64);

        float4 bv = *(const float4*)&base[(size_t)v * 64 + l * 4];
        float dv = dis[v];
        a0 = bv.x + dv * a0;
        a1 = bv.y + dv * a1;
        a2 = bv.z + dv * a2;
        a3 = bv.w + dv * a3;
        // layernorm: intra-group (16 lanes) reduction covers all 64 features
        float m = a0 + a1 + a2 + a3;
        m += __shfl_xor(m, 1, 64); m += __shfl_xor(m, 2, 64);
        m += __shfl_xor(m, 4, 64); m += __shfl_xor(m, 8, 64);
        m *= (1.f / 64.f);
        float d0 = a0 - m, d1 = a1 - m, d2 = a2 - m, d3 = a3 - m;
        float var = d0 * d0 + d1 * d1 + d2 * d2 + d3 * d3;
        var += __shfl_xor(var, 1, 64); var += __shfl_xor(var, 2, 64);
        var += __shfl_xor(var, 4, 64); var += __shfl_xor(var, 8, 64);
        var *= (1.f / 64.f);
        float rs = rsqrtf(var + 1e-5f);
        float y0 = d0 * rs * ldf(gam, l * 4 + 0, f32) + ldf(bet, l * 4 + 0, f32);
        float y1 = d1 * rs * ldf(gam, l * 4 + 1, f32) + ldf(bet, l * 4 + 1, f32);
        float y2 = d2 * rs * ldf(gam, l * 4 + 2, f32) + ldf(bet, l * 4 + 2, f32);
        float y3 = d3 * rs * ldf(gam, l * 4 + 3, f32) + ldf(bet, l * 4 + 3, f32);
        if (relu) {
            y0 = fmaxf(y0, 0.f); y1 = fmaxf(y1, 0.f);
            y2 = fmaxf(y2, 0.f); y3 = fmaxf(y3, 0.f);
        }
        if (!FINAL) {
            if (g == 0)
                *(float4*)&xout[(size_t)v * 64 + l * 4] = make_float4(y0, y1, y2, y3);
        } else {
            float val = y0 * ldf(lw, l * 4 + 0, f32) + y1 * ldf(lw, l * 4 + 1, f32)
                      + y2 * ldf(lw, l * 4 + 2, f32) + y3 * ldf(lw, l * 4 + 3, f32);
            val += __shfl_xor(val, 1, 64); val += __shfl_xor(val, 2, 64);
            val += __shfl_xor(val, 4, 64); val += __shfl_xor(val, 8, 64);
            if (lane == 0) atomicAdd(&sG[batch[v]], val);
        }
    }
    if (FINAL) {
        __syncthreads();
        if (t < NGRAPH && sG[t] != 0.f) atomicAdd(&gsum[t], sG[t]);
    }
}

// ---------------- finalize ----------------
__global__ void k_final(const float* __restrict__ gsum, const int* __restrict__ gcnt,
                        const void* __restrict__ lb, const int* __restrict__ dflag,
                        void* __restrict__ out, int g) {
    int f32 = *dflag;
    int i = threadIdx.x;
    if (i < g) {
        float c = fmaxf((float)gcnt[i], 1.f);
        float v = gsum[i] / c + ldf(lb, 0, f32);
        if (f32) ((float*)out)[i] = v;
        else ((__hip_bfloat16*)out)[i] = __float2bfloat16(v);
    }
}

extern "C" void kernel_launch(void* const* d_in, const int* in_sizes, int n_in,
                              void* d_out, int out_size, void* d_ws, size_t ws_size,
                              hipStream_t stream) {
    const void* x_in = d_in[0];
    const int* edge_index = (const int*)d_in[1];
    const int* batch = (const int*)d_in[2];
    const void *W0 = d_in[3], *b0 = d_in[4], *W1 = d_in[5], *b1 = d_in[6],
               *W2 = d_in[7], *b2 = d_in[8];
    const void *RW0 = d_in[9], *rb0 = d_in[10], *RW1 = d_in[11], *rb1 = d_in[12],
               *RW2 = d_in[13], *rb2 = d_in[14];
    const void *g0 = d_in[15], *be0 = d_in[16], *g1 = d_in[17], *be1 = d_in[18],
               *g2 = d_in[19], *be2 = d_in[20], *lw = d_in[21], *lb = d_in[22];

    const int N = in_sizes[2];
    const int E = in_sizes[1] / 2;
    const int* erow = edge_index;
    const int* ecol = edge_index + E;
    const int nbuck = (N + 127) >> BSH;
    const int T = nbuck * NCH;               // histogram entries

    // workspace carve (~45 MB)
    char* p = (char*)d_ws;
    size_t off = 0;
    float* dis = (float*)(p + off);  off = align256(off + (size_t)N * 4);
    int* offs = (int*)(p + off);     off = align256(off + (size_t)(N + 1) * 4);
    int* csr = (int*)(p + off);      off = align256(off + (size_t)E * 4);
    int2* ebuf = (int2*)(p + off);   off = align256(off + (size_t)E * 8);
    int* hist = (int*)(p + off);     off = align256(off + (size_t)T * 4);
    int* hoffs = (int*)(p + off);    off = align256(off + (size_t)(T + 1) * 4);
    __hip_bfloat16* hs = (__hip_bfloat16*)(p + off); off = align256(off + (size_t)N * HID * 2);
    float* base = (float*)(p + off); off = align256(off + (size_t)N * HID * 4);
    float* xbuf = (float*)(p + off); off = align256(off + (size_t)N * HID * 4);
    unsigned short* wt0 = (unsigned short*)(p + off); off = align256(off + 16384 * 2);
    unsigned short* wt1 = (unsigned short*)(p + off); off = align256(off + 8192 * 2);
    unsigned short* wt2 = (unsigned short*)(p + off); off = align256(off + 8192 * 2);
    float* bcat = (float*)(p + off); off = align256(off + 192 * 4);
    int* bsum = (int*)(p + off);     off = align256(off + 256 * 4);
    int* bscan = (int*)(p + off);    off = align256(off + 256 * 4);
    float* gsum = (float*)(p + off); off = align256(off + NGRAPH * 4);
    int* gcnt = (int*)(p + off);     off = align256(off + NGRAPH * 4);
    int* dflag = (int*)(p + off);    off = align256(off + 4);
    (void)ws_size;

    const int TB = 256;
    int nb_n = (N + TB - 1) / TB;
    int nbT = (T + 1023) / 1024;
    int nb_gemm = (N + 63) / 64;
    int nb_node4 = (N + 3) / 4;

    k_sniff<<<1, 256, 0, stream>>>((const unsigned short*)x_in, 8192, dflag, gsum, gcnt);
    k_gcnt<<<nb_n, TB, 0, stream>>>(batch, gcnt, N);
    k_pack<<<130, TB, 0, stream>>>(W0, RW0, b0, rb0, W1, RW1, b1, rb1, W2, RW2, b2, rb2,
                                   dflag, wt0, wt1, wt2, bcat);
    k_hist<<<NCH, TB, 0, stream>>>(ecol, E, nbuck, hist);
    k_scan1<<<nbT, TB, 0, stream>>>(hist, bsum, T);
    k_scan2<<<1, TB, 0, stream>>>(bsum, bscan, hoffs, nbT, T);
    k_scan3<<<nbT, TB, 0, stream>>>(hist, bscan, hoffs, T);
    k_scatter<<<NCH, TB, 0, stream>>>(erow, ecol, E, nbuck, hoffs, ebuf);
    k_bucket<<<nbuck, TB, 0, stream>>>(ebuf, hoffs, nbuck, N, E, offs, dis, csr);

    // layer 0 (K=128, x dtype per flag)
    k_gemm<128, true, false><<<nb_gemm, TB, 0, stream>>>(x_in, wt0, bcat, dis, dflag, hs, base, N);
    k_agg_ln<false><<<nb_node4, TB, 0, stream>>>(hs, base, dis, offs, csr, g0, be0, dflag,
                                                 xbuf, N, 1, nullptr, nullptr, nullptr);
    // layer 1 (K=64, fp32 x, hi/lo split)
    k_gemm<64, false, true><<<nb_gemm, TB, 0, stream>>>(xbuf, wt1, bcat + 64, dis, dflag, hs, base, N);
    k_agg_ln<false><<<nb_node4, TB, 0, stream>>>(hs, base, dis, offs, csr, g1, be1, dflag,
                                                 xbuf, N, 1, nullptr, nullptr, nullptr);
    // layer 2 (no relu, fused readout)
    k_gemm<64, false, true><<<nb_gemm, TB, 0, stream>>>(xbuf, wt2, bcat + 128, dis, dflag, hs, base, N);
    k_agg_ln<true><<<nb_node4, TB, 0, stream>>>(hs, base, dis, offs, csr, g2, be2, dflag,
                                                nullptr, N, 0, batch, lw, gsum);

    k_final<<<1, 64, 0, stream>>>(gsum, gcnt, lb, dflag, d_out, NGRAPH);
}